// Round 1
// baseline (305.605 us; speedup 1.0000x reference)
//
#include <hip/hip_runtime.h>
#include <math.h>

#define B_ 4
#define L_ 4096
#define D_ 256
#define N_ 16
#define DTR 16
#define NC 32
#define LC 128
#define M_ (B_*L_)

__device__ __forceinline__ float silu_f(float v) { return v / (1.f + __expf(-v)); }

// ---------------- GEMM: C = A(M,256) @ W(256,256) + bias ----------------
// FUSE=1: A element = y*silu(lin)+x  (gated residual prologue of final proj)
#define BM 64
#define BN 64
#define BK 16

template<int FUSE>
__global__ __launch_bounds__(256) void gemm_k(
    const float* __restrict__ Asrc, const float* __restrict__ W,
    const float* __restrict__ bias, const float* __restrict__ lin,
    const float* __restrict__ xin, float* __restrict__ Cout)
{
  __shared__ float As[BK][BM + 1];
  __shared__ float Bs[BK][BN];
  const int tid = threadIdx.x;
  const int bx = blockIdx.x & 3;        // D_/BN = 4 col tiles
  const int by = blockIdx.x >> 2;       // 256 row tiles
  const int row0 = by * BM, col0 = bx * BN;
  const int lm = tid >> 2, lkq = (tid & 3) * 4;   // A-tile load coords
  const int lk = tid >> 4, lnq = (tid & 15) * 4;  // B-tile load coords
  const int ty = tid >> 4, tx = tid & 15;
  float acc[4][4] = {};
  for (int k0 = 0; k0 < 256; k0 += BK) {
    float4 a;
    const int off = (row0 + lm) * 256 + k0 + lkq;
    if constexpr (FUSE) {
      float4 yv = *(const float4*)(Asrc + off);
      float4 lv = *(const float4*)(lin + off);
      float4 xv = *(const float4*)(xin + off);
      a.x = fmaf(yv.x, silu_f(lv.x), xv.x);
      a.y = fmaf(yv.y, silu_f(lv.y), xv.y);
      a.z = fmaf(yv.z, silu_f(lv.z), xv.z);
      a.w = fmaf(yv.w, silu_f(lv.w), xv.w);
    } else {
      a = *(const float4*)(Asrc + off);
    }
    As[lkq + 0][lm] = a.x;
    As[lkq + 1][lm] = a.y;
    As[lkq + 2][lm] = a.z;
    As[lkq + 3][lm] = a.w;
    *(float4*)&Bs[lk][lnq] = *(const float4*)(W + (k0 + lk) * 256 + col0 + lnq);
    __syncthreads();
    #pragma unroll
    for (int kk = 0; kk < BK; ++kk) {
      const float a0 = As[kk][ty * 4 + 0], a1 = As[kk][ty * 4 + 1],
                  a2 = As[kk][ty * 4 + 2], a3 = As[kk][ty * 4 + 3];
      const float4 bv = *(const float4*)&Bs[kk][tx * 4];
      acc[0][0] = fmaf(a0, bv.x, acc[0][0]); acc[0][1] = fmaf(a0, bv.y, acc[0][1]);
      acc[0][2] = fmaf(a0, bv.z, acc[0][2]); acc[0][3] = fmaf(a0, bv.w, acc[0][3]);
      acc[1][0] = fmaf(a1, bv.x, acc[1][0]); acc[1][1] = fmaf(a1, bv.y, acc[1][1]);
      acc[1][2] = fmaf(a1, bv.z, acc[1][2]); acc[1][3] = fmaf(a1, bv.w, acc[1][3]);
      acc[2][0] = fmaf(a2, bv.x, acc[2][0]); acc[2][1] = fmaf(a2, bv.y, acc[2][1]);
      acc[2][2] = fmaf(a2, bv.z, acc[2][2]); acc[2][3] = fmaf(a2, bv.w, acc[2][3]);
      acc[3][0] = fmaf(a3, bv.x, acc[3][0]); acc[3][1] = fmaf(a3, bv.y, acc[3][1]);
      acc[3][2] = fmaf(a3, bv.z, acc[3][2]); acc[3][3] = fmaf(a3, bv.w, acc[3][3]);
    }
    __syncthreads();
  }
  const float4 bb = *(const float4*)(bias + col0 + tx * 4);
  #pragma unroll
  for (int i = 0; i < 4; ++i) {
    float4 o;
    o.x = acc[i][0] + bb.x; o.y = acc[i][1] + bb.y;
    o.z = acc[i][2] + bb.z; o.w = acc[i][3] + bb.w;
    *(float4*)(Cout + (row0 + ty * 4 + i) * 256 + col0 + tx * 4) = o;
  }
}

// ------------- conv3(depthwise)+silu, dbc proj, delta proj -------------
__global__ __launch_bounds__(256) void conv_dbc_delta_k(
    const float* __restrict__ lin, const float* __restrict__ conv_w,
    const float* __restrict__ conv_b, const float* __restrict__ Wdbc,
    const float* __restrict__ Wdt, const float* __restrict__ bdt,
    float* __restrict__ xconv, float* __restrict__ delta,
    float* __restrict__ Bm, float* __restrict__ Cm)
{
  __shared__ float xc[64][D_];      // 64 KB
  __shared__ float dlow[64][DTR];   // 4 KB
  const int b  = blockIdx.x >> 6;   // 64 l-tiles per batch
  const int l0 = (blockIdx.x & 63) * 64;
  const int tid = threadIdx.x;

  // step 1: depthwise conv (taps l-1,l,l+1) + bias + silu
  for (int i = tid; i < 64 * D_; i += 256) {
    const int r = i >> 8, d = i & 255;
    const int l = l0 + r;
    const int base = (b * L_ + l) * D_ + d;
    const float c0 = (l > 0)      ? lin[base - D_] : 0.f;
    const float c1 = lin[base];
    const float c2 = (l < L_ - 1) ? lin[base + D_] : 0.f;
    float v = c0 * conv_w[d * 3 + 0] + c1 * conv_w[d * 3 + 1]
            + c2 * conv_w[d * 3 + 2] + conv_b[d];
    v = silu_f(v);
    xc[r][d] = v;
    xconv[base] = v;
  }
  __syncthreads();

  // step 2: dbc = xc @ W_dbc  (256 -> 48), scatter to dlow / Bm / Cm
  for (int i = tid; i < 64 * 48; i += 256) {
    const int r = i / 48, j = i % 48;
    float s = 0.f;
    #pragma unroll 8
    for (int k = 0; k < D_; ++k) s = fmaf(xc[r][k], Wdbc[k * 48 + j], s);
    const int l = l0 + r;
    if (j < DTR)            dlow[r][j] = s;
    else if (j < DTR + N_)  Bm[(b * L_ + l) * N_ + (j - DTR)] = s;
    else                    Cm[(b * L_ + l) * N_ + (j - DTR - N_)] = s;
  }
  __syncthreads();

  // step 3: delta = softplus(dlow @ W_dt + b_dt)  (16 -> 256)
  for (int i = tid; i < 64 * D_; i += 256) {
    const int r = i >> 8, d = i & 255;
    float s = bdt[d];
    #pragma unroll
    for (int k = 0; k < DTR; ++k) s = fmaf(dlow[r][k], Wdt[k * D_ + d], s);
    const float sp = fmaxf(s, 0.f) + log1pf(expf(-fabsf(s)));
    delta[(b * L_ + (l0 + r)) * D_ + d] = sp;
  }
}

// --------- chunked selective scan: pass1 (per-chunk P,S from h=0) ---------
__global__ __launch_bounds__(256) void scan_pass1_k(
    const float* __restrict__ delta, const float* __restrict__ xconv,
    const float* __restrict__ Bm, const float* __restrict__ A_log,
    float* __restrict__ Pp, float* __restrict__ Sp)
{
  const int gid = blockIdx.x * 256 + threadIdx.x;
  const int n = gid & 15;
  const int g = gid >> 4;              // (b*NC + c)*D + d
  const int d = g & 255;
  const int bc = g >> 8;
  const int c = bc & (NC - 1);
  const int b = bc >> 5;
  const float A = -expf(A_log[d * N_ + n]);
  float P = 1.f, S = 0.f;
  int base = (b * L_ + c * LC) * D_ + d;
  int bn   = (b * L_ + c * LC) * N_ + n;
  for (int t = 0; t < LC; ++t) {
    const float dv = delta[base];
    const float xv = xconv[base];
    const float bv = Bm[bn];
    const float a = __expf(dv * A);
    S = fmaf(a, S, dv * bv * xv);
    P *= a;
    base += D_; bn += N_;
  }
  const int o = ((b * D_ + d) * NC + c) * N_ + n;
  Pp[o] = P; Sp[o] = S;
}

// --------- pass2: tiny cross-chunk scan to get h_in per chunk ---------
__global__ __launch_bounds__(256) void scan_pass2_k(
    const float* __restrict__ Pp, const float* __restrict__ Sp,
    float* __restrict__ Hin)
{
  const int gid = blockIdx.x * 256 + threadIdx.x;  // (b*D+d)*N + n
  const int n = gid & 15;
  const int bd = gid >> 4;
  const int base = bd * NC * N_ + n;
  float h = 0.f;
  for (int c = 0; c < NC; ++c) {
    Hin[base + c * N_] = h;
    h = fmaf(Pp[base + c * N_], h, Sp[base + c * N_]);
  }
}

// --------- pass3: replay chunk from h_in, reduce y over n ---------
__global__ __launch_bounds__(256) void scan_pass3_k(
    const float* __restrict__ delta, const float* __restrict__ xconv,
    const float* __restrict__ Bm, const float* __restrict__ Cm,
    const float* __restrict__ A_log, const float* __restrict__ Dskip,
    const float* __restrict__ Hin, float* __restrict__ y)
{
  const int gid = blockIdx.x * 256 + threadIdx.x;
  const int n = gid & 15;
  const int g = gid >> 4;
  const int d = g & 255;
  const int bc = g >> 8;
  const int c = bc & (NC - 1);
  const int b = bc >> 5;
  const float A = -expf(A_log[d * N_ + n]);
  const float dsk = Dskip[d];
  float h = Hin[((b * D_ + d) * NC + c) * N_ + n];
  int base = (b * L_ + c * LC) * D_ + d;
  int bn   = (b * L_ + c * LC) * N_ + n;
  for (int t = 0; t < LC; ++t) {
    const float dv = delta[base];
    const float xv = xconv[base];
    const float bv = Bm[bn];
    const float cv = Cm[bn];
    const float a = __expf(dv * A);
    h = fmaf(a, h, dv * bv * xv);
    float p = h * cv;
    p += __shfl_xor(p, 1, 16);
    p += __shfl_xor(p, 2, 16);
    p += __shfl_xor(p, 4, 16);
    p += __shfl_xor(p, 8, 16);
    if (n == 0) y[base] = fmaf(dsk, xv, p);
    base += D_; bn += N_;
  }
}

extern "C" void kernel_launch(void* const* d_in, const int* in_sizes, int n_in,
                              void* d_out, int out_size, void* d_ws, size_t ws_size,
                              hipStream_t stream) {
  const float* x      = (const float*)d_in[0];
  const float* W_proj = (const float*)d_in[1];
  const float* b_proj = (const float*)d_in[2];
  const float* conv_w = (const float*)d_in[3];
  const float* conv_b = (const float*)d_in[4];
  const float* W_dbc  = (const float*)d_in[5];
  const float* W_dt   = (const float*)d_in[6];
  const float* b_dt   = (const float*)d_in[7];
  const float* A_log  = (const float*)d_in[8];
  const float* D_skip = (const float*)d_in[9];
  float* out = (float*)d_out;

  float* ws    = (float*)d_ws;
  const size_t SZ = (size_t)M_ * D_;        // 4M floats
  float* lin   = ws;
  float* xconv = ws + SZ;
  float* delta = ws + 2 * SZ;
  float* yb    = ws + 3 * SZ;
  float* Bm    = ws + 4 * SZ;
  float* Cm    = Bm + (size_t)M_ * N_;
  float* Pp    = Cm + (size_t)M_ * N_;
  float* Sp    = Pp + (size_t)B_ * D_ * NC * N_;
  float* Hin   = Sp + (size_t)B_ * D_ * NC * N_;

  // 1. lin = x @ W_proj + b_proj
  gemm_k<0><<<dim3(1024), dim3(256), 0, stream>>>(x, W_proj, b_proj, nullptr, nullptr, lin);
  // 2. conv+silu -> xconv; dbc -> (dlow,B,C); delta = softplus(dlow@W_dt+b_dt)
  conv_dbc_delta_k<<<dim3(256), dim3(256), 0, stream>>>(
      lin, conv_w, conv_b, W_dbc, W_dt, b_dt, xconv, delta, Bm, Cm);
  // 3. chunked scan
  scan_pass1_k<<<dim3(2048), dim3(256), 0, stream>>>(delta, xconv, Bm, A_log, Pp, Sp);
  scan_pass2_k<<<dim3(64), dim3(256), 0, stream>>>(Pp, Sp, Hin);
  scan_pass3_k<<<dim3(2048), dim3(256), 0, stream>>>(delta, xconv, Bm, Cm, A_log, D_skip, Hin, yb);
  // 4. out = (y*silu(lin)+x) @ W_proj + b_proj
  gemm_k<1><<<dim3(1024), dim3(256), 0, stream>>>(yb, W_proj, b_proj, lin, x, out);
}

// Round 2
// 219.255 us; speedup vs baseline: 1.3938x; 1.3938x over previous
//
#include <hip/hip_runtime.h>
#include <math.h>

#define B_ 4
#define L_ 4096
#define D_ 256
#define N_ 16
#define DTR 16
#define NC 32
#define LC 128
#define M_ (B_*L_)

__device__ __forceinline__ float silu_f(float v) { return v / (1.f + __expf(-v)); }

// ---------------- GEMM: C = A(M,256) @ W(256,256) + bias ----------------
// FUSE=1: A element = y*silu(lin)+x  (gated residual prologue of final proj)
#define BM 64
#define BN 64
#define BK 16

template<int FUSE>
__global__ __launch_bounds__(256) void gemm_k(
    const float* __restrict__ Asrc, const float* __restrict__ W,
    const float* __restrict__ bias, const float* __restrict__ lin,
    const float* __restrict__ xin, float* __restrict__ Cout)
{
  __shared__ float As[BK][BM + 1];
  __shared__ float Bs[BK][BN];
  const int tid = threadIdx.x;
  const int bx = blockIdx.x & 3;        // D_/BN = 4 col tiles
  const int by = blockIdx.x >> 2;       // 256 row tiles
  const int row0 = by * BM, col0 = bx * BN;
  const int lm = tid >> 2, lkq = (tid & 3) * 4;   // A-tile load coords
  const int lk = tid >> 4, lnq = (tid & 15) * 4;  // B-tile load coords
  const int ty = tid >> 4, tx = tid & 15;
  float acc[4][4] = {};
  for (int k0 = 0; k0 < 256; k0 += BK) {
    float4 a;
    const int off = (row0 + lm) * 256 + k0 + lkq;
    if constexpr (FUSE) {
      float4 yv = *(const float4*)(Asrc + off);
      float4 lv = *(const float4*)(lin + off);
      float4 xv = *(const float4*)(xin + off);
      a.x = fmaf(yv.x, silu_f(lv.x), xv.x);
      a.y = fmaf(yv.y, silu_f(lv.y), xv.y);
      a.z = fmaf(yv.z, silu_f(lv.z), xv.z);
      a.w = fmaf(yv.w, silu_f(lv.w), xv.w);
    } else {
      a = *(const float4*)(Asrc + off);
    }
    As[lkq + 0][lm] = a.x;
    As[lkq + 1][lm] = a.y;
    As[lkq + 2][lm] = a.z;
    As[lkq + 3][lm] = a.w;
    *(float4*)&Bs[lk][lnq] = *(const float4*)(W + (k0 + lk) * 256 + col0 + lnq);
    __syncthreads();
    #pragma unroll
    for (int kk = 0; kk < BK; ++kk) {
      const float a0 = As[kk][ty * 4 + 0], a1 = As[kk][ty * 4 + 1],
                  a2 = As[kk][ty * 4 + 2], a3 = As[kk][ty * 4 + 3];
      const float4 bv = *(const float4*)&Bs[kk][tx * 4];
      acc[0][0] = fmaf(a0, bv.x, acc[0][0]); acc[0][1] = fmaf(a0, bv.y, acc[0][1]);
      acc[0][2] = fmaf(a0, bv.z, acc[0][2]); acc[0][3] = fmaf(a0, bv.w, acc[0][3]);
      acc[1][0] = fmaf(a1, bv.x, acc[1][0]); acc[1][1] = fmaf(a1, bv.y, acc[1][1]);
      acc[1][2] = fmaf(a1, bv.z, acc[1][2]); acc[1][3] = fmaf(a1, bv.w, acc[1][3]);
      acc[2][0] = fmaf(a2, bv.x, acc[2][0]); acc[2][1] = fmaf(a2, bv.y, acc[2][1]);
      acc[2][2] = fmaf(a2, bv.z, acc[2][2]); acc[2][3] = fmaf(a2, bv.w, acc[2][3]);
      acc[3][0] = fmaf(a3, bv.x, acc[3][0]); acc[3][1] = fmaf(a3, bv.y, acc[3][1]);
      acc[3][2] = fmaf(a3, bv.z, acc[3][2]); acc[3][3] = fmaf(a3, bv.w, acc[3][3]);
    }
    __syncthreads();
  }
  const float4 bb = *(const float4*)(bias + col0 + tx * 4);
  #pragma unroll
  for (int i = 0; i < 4; ++i) {
    float4 o;
    o.x = acc[i][0] + bb.x; o.y = acc[i][1] + bb.y;
    o.z = acc[i][2] + bb.z; o.w = acc[i][3] + bb.w;
    *(float4*)(Cout + (row0 + ty * 4 + i) * 256 + col0 + tx * 4) = o;
  }
}

// ------------- conv3(depthwise)+silu, dbc proj, delta proj -------------
// 512 threads, 64-row tile. Register-tiled 2x3 GEMM for the dbc projection,
// W_dbc transposed in LDS, float4 LDS reads, stride-260 padding (16B-aligned,
// conflict-free).
#define XPAD 260

__global__ __launch_bounds__(512) void conv_dbc_delta_k(
    const float* __restrict__ lin, const float* __restrict__ conv_w,
    const float* __restrict__ conv_b, const float* __restrict__ Wdbc,
    const float* __restrict__ Wdt, const float* __restrict__ bdt,
    float* __restrict__ xconv, float* __restrict__ delta,
    float* __restrict__ Bm, float* __restrict__ Cm)
{
  __shared__ float xc[64][XPAD];     // 66.6 KB
  __shared__ float wt[48][XPAD];     // 49.9 KB  (W_dbc transposed: wt[j][k])
  __shared__ float dlow[64][17];     // 4.4 KB
  const int b  = blockIdx.x >> 6;    // 64 l-tiles per batch
  const int l0 = (blockIdx.x & 63) * 64;
  const int tid = threadIdx.x;

  // step 0: stage W_dbc transposed (48KB, one-time)
  for (int i = tid; i < 48 * D_; i += 512) {
    const int k = i / 48, j = i % 48;          // coalesced read of W_dbc[k][j]
    wt[j][k] = Wdbc[i];
  }

  // step 1: depthwise conv (taps l-1,l,l+1) + bias + silu, float4 over d
  for (int q = tid; q < 64 * 64; q += 512) {
    const int r = q >> 6, dq = (q & 63) * 4;
    const int l = l0 + r;
    const int base = (b * L_ + l) * D_ + dq;
    float4 c0 = (l > 0)      ? *(const float4*)(lin + base - D_) : make_float4(0,0,0,0);
    float4 c1 = *(const float4*)(lin + base);
    float4 c2 = (l < L_ - 1) ? *(const float4*)(lin + base + D_) : make_float4(0,0,0,0);
    float4 v;
    v.x = silu_f(c0.x*conv_w[(dq+0)*3+0] + c1.x*conv_w[(dq+0)*3+1] + c2.x*conv_w[(dq+0)*3+2] + conv_b[dq+0]);
    v.y = silu_f(c0.y*conv_w[(dq+1)*3+0] + c1.y*conv_w[(dq+1)*3+1] + c2.y*conv_w[(dq+1)*3+2] + conv_b[dq+1]);
    v.z = silu_f(c0.z*conv_w[(dq+2)*3+0] + c1.z*conv_w[(dq+2)*3+1] + c2.z*conv_w[(dq+2)*3+2] + conv_b[dq+2]);
    v.w = silu_f(c0.w*conv_w[(dq+3)*3+0] + c1.w*conv_w[(dq+3)*3+1] + c2.w*conv_w[(dq+3)*3+2] + conv_b[dq+3]);
    *(float4*)&xc[r][dq] = v;
    *(float4*)(xconv + base) = v;
  }
  __syncthreads();

  // step 2: dbc = xc @ W_dbc (256 -> 48); thread tile 2 rows x 3 cols
  {
    const int ty = tid >> 4;          // 0..31 -> rows ty*2, ty*2+1
    const int tx = tid & 15;          // 0..15 -> cols tx*3..tx*3+2
    const int r0 = ty * 2, j0 = tx * 3;
    float acc[2][3] = {};
    #pragma unroll 4
    for (int k0 = 0; k0 < D_; k0 += 4) {
      const float4 x0 = *(const float4*)&xc[r0 + 0][k0];
      const float4 x1 = *(const float4*)&xc[r0 + 1][k0];
      const float4 w0 = *(const float4*)&wt[j0 + 0][k0];
      const float4 w1 = *(const float4*)&wt[j0 + 1][k0];
      const float4 w2 = *(const float4*)&wt[j0 + 2][k0];
      acc[0][0] += x0.x*w0.x + x0.y*w0.y + x0.z*w0.z + x0.w*w0.w;
      acc[0][1] += x0.x*w1.x + x0.y*w1.y + x0.z*w1.z + x0.w*w1.w;
      acc[0][2] += x0.x*w2.x + x0.y*w2.y + x0.z*w2.z + x0.w*w2.w;
      acc[1][0] += x1.x*w0.x + x1.y*w0.y + x1.z*w0.z + x1.w*w0.w;
      acc[1][1] += x1.x*w1.x + x1.y*w1.y + x1.z*w1.z + x1.w*w1.w;
      acc[1][2] += x1.x*w2.x + x1.y*w2.y + x1.z*w2.z + x1.w*w2.w;
    }
    #pragma unroll
    for (int i = 0; i < 2; ++i) {
      #pragma unroll
      for (int jj = 0; jj < 3; ++jj) {
        const float s = acc[i][jj];
        const int r = r0 + i, j = j0 + jj;
        const int l = l0 + r;
        if (j < DTR)            dlow[r][j] = s;
        else if (j < DTR + N_)  Bm[(b * L_ + l) * N_ + (j - DTR)] = s;
        else                    Cm[(b * L_ + l) * N_ + (j - DTR - N_)] = s;
      }
    }
  }
  __syncthreads();

  // step 3: delta = softplus(dlow @ W_dt + b_dt)  (16 -> 256), float4 over d
  for (int q = tid; q < 64 * 64; q += 512) {
    const int r = q >> 6, dq = (q & 63) * 4;
    float4 s = *(const float4*)(bdt + dq);
    #pragma unroll
    for (int k = 0; k < DTR; ++k) {
      const float f = dlow[r][k];
      const float4 wv = *(const float4*)(Wdt + k * D_ + dq);
      s.x = fmaf(f, wv.x, s.x); s.y = fmaf(f, wv.y, s.y);
      s.z = fmaf(f, wv.z, s.z); s.w = fmaf(f, wv.w, s.w);
    }
    float4 o;
    o.x = fmaxf(s.x, 0.f) + log1pf(expf(-fabsf(s.x)));
    o.y = fmaxf(s.y, 0.f) + log1pf(expf(-fabsf(s.y)));
    o.z = fmaxf(s.z, 0.f) + log1pf(expf(-fabsf(s.z)));
    o.w = fmaxf(s.w, 0.f) + log1pf(expf(-fabsf(s.w)));
    *(float4*)(delta + (b * L_ + (l0 + r)) * D_ + dq) = o;
  }
}

// --------- chunked selective scan: pass1 (per-chunk P,S from h=0) ---------
__global__ __launch_bounds__(256) void scan_pass1_k(
    const float* __restrict__ delta, const float* __restrict__ xconv,
    const float* __restrict__ Bm, const float* __restrict__ A_log,
    float* __restrict__ Pp, float* __restrict__ Sp)
{
  const int gid = blockIdx.x * 256 + threadIdx.x;
  const int n = gid & 15;
  const int g = gid >> 4;              // (b*NC + c)*D + d
  const int d = g & 255;
  const int bc = g >> 8;
  const int c = bc & (NC - 1);
  const int b = bc >> 5;
  const float A = -expf(A_log[d * N_ + n]);
  float P = 1.f, S = 0.f;
  int base = (b * L_ + c * LC) * D_ + d;
  int bn   = (b * L_ + c * LC) * N_ + n;
  for (int t = 0; t < LC; ++t) {
    const float dv = delta[base];
    const float xv = xconv[base];
    const float bv = Bm[bn];
    const float a = __expf(dv * A);
    S = fmaf(a, S, dv * bv * xv);
    P *= a;
    base += D_; bn += N_;
  }
  const int o = ((b * D_ + d) * NC + c) * N_ + n;
  Pp[o] = P; Sp[o] = S;
}

// --------- pass2: tiny cross-chunk scan to get h_in per chunk ---------
__global__ __launch_bounds__(256) void scan_pass2_k(
    const float* __restrict__ Pp, const float* __restrict__ Sp,
    float* __restrict__ Hin)
{
  const int gid = blockIdx.x * 256 + threadIdx.x;  // (b*D+d)*N + n
  const int n = gid & 15;
  const int bd = gid >> 4;
  const int base = bd * NC * N_ + n;
  float h = 0.f;
  for (int c = 0; c < NC; ++c) {
    Hin[base + c * N_] = h;
    h = fmaf(Pp[base + c * N_], h, Sp[base + c * N_]);
  }
}

// --------- pass3: replay chunk from h_in, reduce y over n ---------
__global__ __launch_bounds__(256) void scan_pass3_k(
    const float* __restrict__ delta, const float* __restrict__ xconv,
    const float* __restrict__ Bm, const float* __restrict__ Cm,
    const float* __restrict__ A_log, const float* __restrict__ Dskip,
    const float* __restrict__ Hin, float* __restrict__ y)
{
  const int gid = blockIdx.x * 256 + threadIdx.x;
  const int n = gid & 15;
  const int g = gid >> 4;
  const int d = g & 255;
  const int bc = g >> 8;
  const int c = bc & (NC - 1);
  const int b = bc >> 5;
  const float A = -expf(A_log[d * N_ + n]);
  const float dsk = Dskip[d];
  float h = Hin[((b * D_ + d) * NC + c) * N_ + n];
  int base = (b * L_ + c * LC) * D_ + d;
  int bn   = (b * L_ + c * LC) * N_ + n;
  for (int t = 0; t < LC; ++t) {
    const float dv = delta[base];
    const float xv = xconv[base];
    const float bv = Bm[bn];
    const float cv = Cm[bn];
    const float a = __expf(dv * A);
    h = fmaf(a, h, dv * bv * xv);
    float p = h * cv;
    p += __shfl_xor(p, 1, 16);
    p += __shfl_xor(p, 2, 16);
    p += __shfl_xor(p, 4, 16);
    p += __shfl_xor(p, 8, 16);
    if (n == 0) y[base] = fmaf(dsk, xv, p);
    base += D_; bn += N_;
  }
}

extern "C" void kernel_launch(void* const* d_in, const int* in_sizes, int n_in,
                              void* d_out, int out_size, void* d_ws, size_t ws_size,
                              hipStream_t stream) {
  const float* x      = (const float*)d_in[0];
  const float* W_proj = (const float*)d_in[1];
  const float* b_proj = (const float*)d_in[2];
  const float* conv_w = (const float*)d_in[3];
  const float* conv_b = (const float*)d_in[4];
  const float* W_dbc  = (const float*)d_in[5];
  const float* W_dt   = (const float*)d_in[6];
  const float* b_dt   = (const float*)d_in[7];
  const float* A_log  = (const float*)d_in[8];
  const float* D_skip = (const float*)d_in[9];
  float* out = (float*)d_out;

  float* ws    = (float*)d_ws;
  const size_t SZ = (size_t)M_ * D_;        // 4M floats
  float* lin   = ws;
  float* xconv = ws + SZ;
  float* delta = ws + 2 * SZ;
  float* yb    = ws + 3 * SZ;
  float* Bm    = ws + 4 * SZ;
  float* Cm    = Bm + (size_t)M_ * N_;
  float* Pp    = Cm + (size_t)M_ * N_;
  float* Sp    = Pp + (size_t)B_ * D_ * NC * N_;
  float* Hin   = Sp + (size_t)B_ * D_ * NC * N_;

  // 1. lin = x @ W_proj + b_proj
  gemm_k<0><<<dim3(1024), dim3(256), 0, stream>>>(x, W_proj, b_proj, nullptr, nullptr, lin);
  // 2. conv+silu -> xconv; dbc -> (dlow,B,C); delta = softplus(dlow@W_dt+b_dt)
  conv_dbc_delta_k<<<dim3(256), dim3(512), 0, stream>>>(
      lin, conv_w, conv_b, W_dbc, W_dt, b_dt, xconv, delta, Bm, Cm);
  // 3. chunked scan
  scan_pass1_k<<<dim3(2048), dim3(256), 0, stream>>>(delta, xconv, Bm, A_log, Pp, Sp);
  scan_pass2_k<<<dim3(64), dim3(256), 0, stream>>>(Pp, Sp, Hin);
  scan_pass3_k<<<dim3(2048), dim3(256), 0, stream>>>(delta, xconv, Bm, Cm, A_log, D_skip, Hin, yb);
  // 4. out = (y*silu(lin)+x) @ W_proj + b_proj
  gemm_k<1><<<dim3(1024), dim3(256), 0, stream>>>(yb, W_proj, b_proj, lin, x, out);
}

// Round 3
// 217.224 us; speedup vs baseline: 1.4069x; 1.0094x over previous
//
#include <hip/hip_runtime.h>
#include <math.h>

#define B_ 4
#define L_ 4096
#define D_ 256
#define N_ 16
#define DTR 16
#define NC 128
#define LC 32
#define M_ (B_*L_)

__device__ __forceinline__ float silu_f(float v) { return v / (1.f + __expf(-v)); }

// ---------------- GEMM: C = A(M,256) @ W(256,256) + bias ----------------
// FUSE=1: A element = y*silu(lin)+x  (gated residual prologue of final proj)
#define BM 64
#define BN 64
#define BK 16

template<int FUSE>
__global__ __launch_bounds__(256) void gemm_k(
    const float* __restrict__ Asrc, const float* __restrict__ W,
    const float* __restrict__ bias, const float* __restrict__ lin,
    const float* __restrict__ xin, float* __restrict__ Cout)
{
  __shared__ float As[BK][BM + 1];
  __shared__ float Bs[BK][BN];
  const int tid = threadIdx.x;
  const int bx = blockIdx.x & 3;        // D_/BN = 4 col tiles
  const int by = blockIdx.x >> 2;       // 256 row tiles
  const int row0 = by * BM, col0 = bx * BN;
  const int lm = tid >> 2, lkq = (tid & 3) * 4;   // A-tile load coords
  const int lk = tid >> 4, lnq = (tid & 15) * 4;  // B-tile load coords
  const int ty = tid >> 4, tx = tid & 15;
  float acc[4][4] = {};
  for (int k0 = 0; k0 < 256; k0 += BK) {
    float4 a;
    const int off = (row0 + lm) * 256 + k0 + lkq;
    if constexpr (FUSE) {
      float4 yv = *(const float4*)(Asrc + off);
      float4 lv = *(const float4*)(lin + off);
      float4 xv = *(const float4*)(xin + off);
      a.x = fmaf(yv.x, silu_f(lv.x), xv.x);
      a.y = fmaf(yv.y, silu_f(lv.y), xv.y);
      a.z = fmaf(yv.z, silu_f(lv.z), xv.z);
      a.w = fmaf(yv.w, silu_f(lv.w), xv.w);
    } else {
      a = *(const float4*)(Asrc + off);
    }
    As[lkq + 0][lm] = a.x;
    As[lkq + 1][lm] = a.y;
    As[lkq + 2][lm] = a.z;
    As[lkq + 3][lm] = a.w;
    *(float4*)&Bs[lk][lnq] = *(const float4*)(W + (k0 + lk) * 256 + col0 + lnq);
    __syncthreads();
    #pragma unroll
    for (int kk = 0; kk < BK; ++kk) {
      const float a0 = As[kk][ty * 4 + 0], a1 = As[kk][ty * 4 + 1],
                  a2 = As[kk][ty * 4 + 2], a3 = As[kk][ty * 4 + 3];
      const float4 bv = *(const float4*)&Bs[kk][tx * 4];
      acc[0][0] = fmaf(a0, bv.x, acc[0][0]); acc[0][1] = fmaf(a0, bv.y, acc[0][1]);
      acc[0][2] = fmaf(a0, bv.z, acc[0][2]); acc[0][3] = fmaf(a0, bv.w, acc[0][3]);
      acc[1][0] = fmaf(a1, bv.x, acc[1][0]); acc[1][1] = fmaf(a1, bv.y, acc[1][1]);
      acc[1][2] = fmaf(a1, bv.z, acc[1][2]); acc[1][3] = fmaf(a1, bv.w, acc[1][3]);
      acc[2][0] = fmaf(a2, bv.x, acc[2][0]); acc[2][1] = fmaf(a2, bv.y, acc[2][1]);
      acc[2][2] = fmaf(a2, bv.z, acc[2][2]); acc[2][3] = fmaf(a2, bv.w, acc[2][3]);
      acc[3][0] = fmaf(a3, bv.x, acc[3][0]); acc[3][1] = fmaf(a3, bv.y, acc[3][1]);
      acc[3][2] = fmaf(a3, bv.z, acc[3][2]); acc[3][3] = fmaf(a3, bv.w, acc[3][3]);
    }
    __syncthreads();
  }
  const float4 bb = *(const float4*)(bias + col0 + tx * 4);
  #pragma unroll
  for (int i = 0; i < 4; ++i) {
    float4 o;
    o.x = acc[i][0] + bb.x; o.y = acc[i][1] + bb.y;
    o.z = acc[i][2] + bb.z; o.w = acc[i][3] + bb.w;
    *(float4*)(Cout + (row0 + ty * 4 + i) * 256 + col0 + tx * 4) = o;
  }
}

// ------------- conv3(depthwise)+silu, dbc proj, delta proj -------------
#define XPAD 260

__global__ __launch_bounds__(512) void conv_dbc_delta_k(
    const float* __restrict__ lin, const float* __restrict__ conv_w,
    const float* __restrict__ conv_b, const float* __restrict__ Wdbc,
    const float* __restrict__ Wdt, const float* __restrict__ bdt,
    float* __restrict__ xconv, float* __restrict__ delta,
    float* __restrict__ Bm, float* __restrict__ Cm)
{
  __shared__ float xc[64][XPAD];     // 66.6 KB
  __shared__ float wt[48][XPAD];     // 49.9 KB  (W_dbc transposed: wt[j][k])
  __shared__ float dlow[64][17];     // 4.4 KB
  const int b  = blockIdx.x >> 6;    // 64 l-tiles per batch
  const int l0 = (blockIdx.x & 63) * 64;
  const int tid = threadIdx.x;

  // step 0: stage W_dbc transposed (48KB, one-time)
  for (int i = tid; i < 48 * D_; i += 512) {
    const int k = i / 48, j = i % 48;          // coalesced read of W_dbc[k][j]
    wt[j][k] = Wdbc[i];
  }

  // step 1: depthwise conv (taps l-1,l,l+1) + bias + silu, float4 over d
  for (int q = tid; q < 64 * 64; q += 512) {
    const int r = q >> 6, dq = (q & 63) * 4;
    const int l = l0 + r;
    const int base = (b * L_ + l) * D_ + dq;
    float4 c0 = (l > 0)      ? *(const float4*)(lin + base - D_) : make_float4(0,0,0,0);
    float4 c1 = *(const float4*)(lin + base);
    float4 c2 = (l < L_ - 1) ? *(const float4*)(lin + base + D_) : make_float4(0,0,0,0);
    float4 v;
    v.x = silu_f(c0.x*conv_w[(dq+0)*3+0] + c1.x*conv_w[(dq+0)*3+1] + c2.x*conv_w[(dq+0)*3+2] + conv_b[dq+0]);
    v.y = silu_f(c0.y*conv_w[(dq+1)*3+0] + c1.y*conv_w[(dq+1)*3+1] + c2.y*conv_w[(dq+1)*3+2] + conv_b[dq+1]);
    v.z = silu_f(c0.z*conv_w[(dq+2)*3+0] + c1.z*conv_w[(dq+2)*3+1] + c2.z*conv_w[(dq+2)*3+2] + conv_b[dq+2]);
    v.w = silu_f(c0.w*conv_w[(dq+3)*3+0] + c1.w*conv_w[(dq+3)*3+1] + c2.w*conv_w[(dq+3)*3+2] + conv_b[dq+3]);
    *(float4*)&xc[r][dq] = v;
    *(float4*)(xconv + base) = v;
  }
  __syncthreads();

  // step 2: dbc = xc @ W_dbc (256 -> 48); thread tile 2 rows x 3 cols
  {
    const int ty = tid >> 4;          // 0..31 -> rows ty*2, ty*2+1
    const int tx = tid & 15;          // 0..15 -> cols tx*3..tx*3+2
    const int r0 = ty * 2, j0 = tx * 3;
    float acc[2][3] = {};
    #pragma unroll 4
    for (int k0 = 0; k0 < D_; k0 += 4) {
      const float4 x0 = *(const float4*)&xc[r0 + 0][k0];
      const float4 x1 = *(const float4*)&xc[r0 + 1][k0];
      const float4 w0 = *(const float4*)&wt[j0 + 0][k0];
      const float4 w1 = *(const float4*)&wt[j0 + 1][k0];
      const float4 w2 = *(const float4*)&wt[j0 + 2][k0];
      acc[0][0] += x0.x*w0.x + x0.y*w0.y + x0.z*w0.z + x0.w*w0.w;
      acc[0][1] += x0.x*w1.x + x0.y*w1.y + x0.z*w1.z + x0.w*w1.w;
      acc[0][2] += x0.x*w2.x + x0.y*w2.y + x0.z*w2.z + x0.w*w2.w;
      acc[1][0] += x1.x*w0.x + x1.y*w0.y + x1.z*w0.z + x1.w*w0.w;
      acc[1][1] += x1.x*w1.x + x1.y*w1.y + x1.z*w1.z + x1.w*w1.w;
      acc[1][2] += x1.x*w2.x + x1.y*w2.y + x1.z*w2.z + x1.w*w2.w;
    }
    #pragma unroll
    for (int i = 0; i < 2; ++i) {
      #pragma unroll
      for (int jj = 0; jj < 3; ++jj) {
        const float s = acc[i][jj];
        const int r = r0 + i, j = j0 + jj;
        const int l = l0 + r;
        if (j < DTR)            dlow[r][j] = s;
        else if (j < DTR + N_)  Bm[(b * L_ + l) * N_ + (j - DTR)] = s;
        else                    Cm[(b * L_ + l) * N_ + (j - DTR - N_)] = s;
      }
    }
  }
  __syncthreads();

  // step 3: delta = softplus(dlow @ W_dt + b_dt)  (16 -> 256), float4 over d
  for (int q = tid; q < 64 * 64; q += 512) {
    const int r = q >> 6, dq = (q & 63) * 4;
    float4 s = *(const float4*)(bdt + dq);
    #pragma unroll
    for (int k = 0; k < DTR; ++k) {
      const float f = dlow[r][k];
      const float4 wv = *(const float4*)(Wdt + k * D_ + dq);
      s.x = fmaf(f, wv.x, s.x); s.y = fmaf(f, wv.y, s.y);
      s.z = fmaf(f, wv.z, s.z); s.w = fmaf(f, wv.w, s.w);
    }
    float4 o;
    o.x = fmaxf(s.x, 0.f) + log1pf(expf(-fabsf(s.x)));
    o.y = fmaxf(s.y, 0.f) + log1pf(expf(-fabsf(s.y)));
    o.z = fmaxf(s.z, 0.f) + log1pf(expf(-fabsf(s.z)));
    o.w = fmaxf(s.w, 0.f) + log1pf(expf(-fabsf(s.w)));
    *(float4*)(delta + (b * L_ + (l0 + r)) * D_ + dq) = o;
  }
}

// --------- chunked selective scan: thread owns (b,chunk,d), n in regs ---------
// pass1: per-chunk P (prod of a) and S (chunk output from h=0)
__global__ __launch_bounds__(256) void scan_pass1_k(
    const float* __restrict__ delta, const float* __restrict__ xconv,
    const float* __restrict__ Bm, const float* __restrict__ A_log,
    float* __restrict__ Pp, float* __restrict__ Sp)
{
  const int gid = blockIdx.x * 256 + threadIdx.x;   // B*NC*D threads
  const int d = gid & 255;
  const int c = (gid >> 8) & (NC - 1);
  const int b = gid >> 15;
  float A[N_], P[N_], S[N_];
  #pragma unroll
  for (int n = 0; n < N_; ++n) {
    A[n] = -__expf(A_log[d * N_ + n]);
    P[n] = 1.f; S[n] = 0.f;
  }
  int base = (b * L_ + c * LC) * D_ + d;
  int bn   = (b * L_ + c * LC) * N_;
  #pragma unroll 2
  for (int t = 0; t < LC; ++t) {
    const float dv = delta[base];
    const float xv = xconv[base];
    const float dvx = dv * xv;
    float bv[N_];
    #pragma unroll
    for (int q = 0; q < 4; ++q) *(float4*)&bv[q * 4] = *(const float4*)(Bm + bn + q * 4);
    #pragma unroll
    for (int n = 0; n < N_; ++n) {
      const float a = __expf(dv * A[n]);
      S[n] = fmaf(a, S[n], dvx * bv[n]);
      P[n] *= a;
    }
    base += D_; bn += N_;
  }
  const int o = ((b * D_ + d) * NC + c) * N_;
  #pragma unroll
  for (int q = 0; q < 4; ++q) {
    *(float4*)(Pp + o + q * 4) = *(const float4*)&P[q * 4];
    *(float4*)(Sp + o + q * 4) = *(const float4*)&S[q * 4];
  }
}

// pass2: cross-chunk scan; Hin may alias Pp (read-before-write order)
__global__ __launch_bounds__(256) void scan_pass2_k(
    const float* Pp, const float* Sp, float* Hin)
{
  const int gid = blockIdx.x * 256 + threadIdx.x;   // B*D*N threads
  const int n = gid & 15;
  const int bd = gid >> 4;
  const int base = bd * NC * N_ + n;
  float h = 0.f;
  for (int c = 0; c < NC; ++c) {
    const int idx = base + c * N_;
    const float p = Pp[idx];
    const float s = Sp[idx];
    Hin[idx] = h;
    h = fmaf(p, h, s);
  }
}

// pass3: replay chunk from h_in, reduce y over n in-register
__global__ __launch_bounds__(256) void scan_pass3_k(
    const float* __restrict__ delta, const float* __restrict__ xconv,
    const float* __restrict__ Bm, const float* __restrict__ Cm,
    const float* __restrict__ A_log, const float* __restrict__ Dskip,
    const float* __restrict__ Hin, float* __restrict__ y)
{
  const int gid = blockIdx.x * 256 + threadIdx.x;   // B*NC*D threads
  const int d = gid & 255;
  const int c = (gid >> 8) & (NC - 1);
  const int b = gid >> 15;
  const float dsk = Dskip[d];
  float A[N_], h[N_];
  const int ho = ((b * D_ + d) * NC + c) * N_;
  #pragma unroll
  for (int n = 0; n < N_; ++n) A[n] = -__expf(A_log[d * N_ + n]);
  #pragma unroll
  for (int q = 0; q < 4; ++q) *(float4*)&h[q * 4] = *(const float4*)(Hin + ho + q * 4);
  int base = (b * L_ + c * LC) * D_ + d;
  int bn   = (b * L_ + c * LC) * N_;
  #pragma unroll 2
  for (int t = 0; t < LC; ++t) {
    const float dv = delta[base];
    const float xv = xconv[base];
    const float dvx = dv * xv;
    float bv[N_], cv[N_];
    #pragma unroll
    for (int q = 0; q < 4; ++q) {
      *(float4*)&bv[q * 4] = *(const float4*)(Bm + bn + q * 4);
      *(float4*)&cv[q * 4] = *(const float4*)(Cm + bn + q * 4);
    }
    float yv = dsk * xv;
    #pragma unroll
    for (int n = 0; n < N_; ++n) {
      const float a = __expf(dv * A[n]);
      h[n] = fmaf(a, h[n], dvx * bv[n]);
      yv = fmaf(h[n], cv[n], yv);
    }
    y[base] = yv;
    base += D_; bn += N_;
  }
}

extern "C" void kernel_launch(void* const* d_in, const int* in_sizes, int n_in,
                              void* d_out, int out_size, void* d_ws, size_t ws_size,
                              hipStream_t stream) {
  const float* x      = (const float*)d_in[0];
  const float* W_proj = (const float*)d_in[1];
  const float* b_proj = (const float*)d_in[2];
  const float* conv_w = (const float*)d_in[3];
  const float* conv_b = (const float*)d_in[4];
  const float* W_dbc  = (const float*)d_in[5];
  const float* W_dt   = (const float*)d_in[6];
  const float* b_dt   = (const float*)d_in[7];
  const float* A_log  = (const float*)d_in[8];
  const float* D_skip = (const float*)d_in[9];
  float* out = (float*)d_out;

  float* ws    = (float*)d_ws;
  const size_t SZ = (size_t)M_ * D_;        // 4M floats
  float* lin   = ws;
  float* xconv = ws + SZ;
  float* delta = ws + 2 * SZ;
  float* yb    = ws + 3 * SZ;
  float* Bm    = ws + 4 * SZ;
  float* Cm    = Bm + (size_t)M_ * N_;
  // Pp/Sp live in d_out (dead until final GEMM); Hin aliases Pp (pass2 is
  // read-before-write at each index).
  const size_t PSZ = (size_t)B_ * D_ * NC * N_;   // 2M floats
  float* Pp  = out;
  float* Sp  = out + PSZ;
  float* Hin = Pp;

  // 1. lin = x @ W_proj + b_proj
  gemm_k<0><<<dim3(1024), dim3(256), 0, stream>>>(x, W_proj, b_proj, nullptr, nullptr, lin);
  // 2. conv+silu -> xconv; dbc -> (dlow,B,C); delta = softplus(dlow@W_dt+b_dt)
  conv_dbc_delta_k<<<dim3(256), dim3(512), 0, stream>>>(
      lin, conv_w, conv_b, W_dbc, W_dt, b_dt, xconv, delta, Bm, Cm);
  // 3. chunked scan (NC=128 chunks of LC=32)
  scan_pass1_k<<<dim3(512), dim3(256), 0, stream>>>(delta, xconv, Bm, A_log, Pp, Sp);
  scan_pass2_k<<<dim3(64), dim3(256), 0, stream>>>(Pp, Sp, Hin);
  scan_pass3_k<<<dim3(512), dim3(256), 0, stream>>>(delta, xconv, Bm, Cm, A_log, D_skip, Hin, yb);
  // 4. out = (y*silu(lin)+x) @ W_proj + b_proj
  gemm_k<1><<<dim3(1024), dim3(256), 0, stream>>>(yb, W_proj, b_proj, lin, x, out);
}

// Round 4
// 160.746 us; speedup vs baseline: 1.9012x; 1.3513x over previous
//
#include <hip/hip_runtime.h>
#include <math.h>

#define B_ 4
#define L_ 4096
#define D_ 256
#define N_ 16
#define DTR 16
#define NC 128
#define LC 32
#define M_ (B_*L_)

typedef __attribute__((ext_vector_type(8))) short short8;
typedef __attribute__((ext_vector_type(4))) float floatx4;

__device__ __forceinline__ float silu_f(float v) { return v / (1.f + __expf(-v)); }

__device__ __forceinline__ unsigned short f2bf(float f) {
  union { float f; unsigned u; } v; v.f = f;
  unsigned r = (v.u + 0x7FFFu + ((v.u >> 16) & 1u)) >> 16;
  return (unsigned short)r;
}

// ---- one-time: Wt[n][k] = bf16(W[k][n]) ----
__global__ __launch_bounds__(256) void convert_w_k(
    const float* __restrict__ W, unsigned short* __restrict__ Wt)
{
  const int k = blockIdx.x;
  const int n = threadIdx.x;
  Wt[n * 256 + k] = f2bf(W[k * 256 + n]);
}

// ---------------- MFMA GEMM: C(M,256) = A(M,256) @ W + bias ----------------
// BM=32 rows/block, BN=256 (full N -> A fetched exactly once).
// FUSE=1: A element = y*silu(lin)+x  (gated residual prologue of final proj)
template<int FUSE>
__global__ __launch_bounds__(256) void gemm_mfma_k(
    const float* __restrict__ Asrc, const unsigned short* __restrict__ Wt,
    const float* __restrict__ bias, const float* __restrict__ lin,
    const float* __restrict__ xin, float* __restrict__ Cout)
{
  __shared__ unsigned short Asl[32][40];    // 32 rows x 32 k (pad->40), bf16
  __shared__ unsigned short Wsl[256][40];   // 256 n  x 32 k (pad->40), bf16
  const int tid = threadIdx.x;
  const int lane = tid & 63, w = tid >> 6;
  const int row0 = blockIdx.x * 32;
  const int l15 = lane & 15, lg = lane >> 4;
  const int arow = (w & 1) * 16 + l15;      // A row this lane feeds
  const int ctile = (w >> 1) * 128;         // this wave's 128-col slab
  const int kk = lg * 8;                    // k-offset within 32-window
  floatx4 acc[8];
  #pragma unroll
  for (int f = 0; f < 8; ++f) acc[f] = (floatx4){0.f, 0.f, 0.f, 0.f};

  const int ar = tid >> 3, akc = (tid & 7) * 4;   // A staging coords
  const int wn = tid >> 2, wkc = (tid & 3) * 8;   // W staging coords

  for (int ks = 0; ks < 8; ++ks) {
    const int k0 = ks * 32;
    __syncthreads();
    // stage A tile (f32 -> bf16), gate fused for FUSE=1
    {
      const int off = (row0 + ar) * 256 + k0 + akc;
      float4 av;
      if constexpr (FUSE) {
        float4 yv = *(const float4*)(Asrc + off);
        float4 lv = *(const float4*)(lin + off);
        float4 xv = *(const float4*)(xin + off);
        av.x = fmaf(yv.x, silu_f(lv.x), xv.x);
        av.y = fmaf(yv.y, silu_f(lv.y), xv.y);
        av.z = fmaf(yv.z, silu_f(lv.z), xv.z);
        av.w = fmaf(yv.w, silu_f(lv.w), xv.w);
      } else {
        av = *(const float4*)(Asrc + off);
      }
      unsigned short* p = &Asl[ar][akc];
      p[0] = f2bf(av.x); p[1] = f2bf(av.y); p[2] = f2bf(av.z); p[3] = f2bf(av.w);
    }
    // stage W tile (already bf16): 4 x 16B per thread
    #pragma unroll
    for (int i = 0; i < 4; ++i) {
      const int n = wn + i * 64;
      *(uint4*)&Wsl[n][wkc] = *(const uint4*)(Wt + n * 256 + k0 + wkc);
    }
    __syncthreads();
    const short8 af = *(const short8*)&Asl[arow][kk];
    #pragma unroll
    for (int f = 0; f < 8; ++f) {
      const short8 bf_ = *(const short8*)&Wsl[ctile + f * 16 + l15][kk];
      acc[f] = __builtin_amdgcn_mfma_f32_16x16x32_bf16(af, bf_, acc[f], 0, 0, 0);
    }
  }
  // epilogue: C/D layout col=lane&15, row=(lane>>4)*4+reg  (m89/m91 verified)
  const int growb = row0 + (w & 1) * 16 + lg * 4;
  #pragma unroll
  for (int f = 0; f < 8; ++f) {
    const int col = ctile + f * 16 + l15;
    const float bb = bias[col];
    #pragma unroll
    for (int r = 0; r < 4; ++r)
      Cout[(growb + r) * 256 + col] = acc[f][r] + bb;
  }
}

// ------------- conv3(depthwise)+silu, dbc proj, delta proj -------------
#define XPAD 260

__global__ __launch_bounds__(512) void conv_dbc_delta_k(
    const float* __restrict__ lin, const float* __restrict__ conv_w,
    const float* __restrict__ conv_b, const float* __restrict__ Wdbc,
    const float* __restrict__ Wdt, const float* __restrict__ bdt,
    float* __restrict__ xconv, float* __restrict__ delta,
    float* __restrict__ Bm, float* __restrict__ Cm)
{
  __shared__ float xc[64][XPAD];     // 66.6 KB
  __shared__ float wt[48][XPAD];     // 49.9 KB  (W_dbc transposed: wt[j][k])
  __shared__ float dlow[64][17];     // 4.4 KB
  const int b  = blockIdx.x >> 6;    // 64 l-tiles per batch
  const int l0 = (blockIdx.x & 63) * 64;
  const int tid = threadIdx.x;

  // step 0: stage W_dbc transposed (48KB, one-time)
  for (int i = tid; i < 48 * D_; i += 512) {
    const int k = i / 48, j = i % 48;          // coalesced read of W_dbc[k][j]
    wt[j][k] = Wdbc[i];
  }

  // step 1: depthwise conv (taps l-1,l,l+1) + bias + silu, float4 over d
  for (int q = tid; q < 64 * 64; q += 512) {
    const int r = q >> 6, dq = (q & 63) * 4;
    const int l = l0 + r;
    const int base = (b * L_ + l) * D_ + dq;
    float4 c0 = (l > 0)      ? *(const float4*)(lin + base - D_) : make_float4(0,0,0,0);
    float4 c1 = *(const float4*)(lin + base);
    float4 c2 = (l < L_ - 1) ? *(const float4*)(lin + base + D_) : make_float4(0,0,0,0);
    float4 v;
    v.x = silu_f(c0.x*conv_w[(dq+0)*3+0] + c1.x*conv_w[(dq+0)*3+1] + c2.x*conv_w[(dq+0)*3+2] + conv_b[dq+0]);
    v.y = silu_f(c0.y*conv_w[(dq+1)*3+0] + c1.y*conv_w[(dq+1)*3+1] + c2.y*conv_w[(dq+1)*3+2] + conv_b[dq+1]);
    v.z = silu_f(c0.z*conv_w[(dq+2)*3+0] + c1.z*conv_w[(dq+2)*3+1] + c2.z*conv_w[(dq+2)*3+2] + conv_b[dq+2]);
    v.w = silu_f(c0.w*conv_w[(dq+3)*3+0] + c1.w*conv_w[(dq+3)*3+1] + c2.w*conv_w[(dq+3)*3+2] + conv_b[dq+3]);
    *(float4*)&xc[r][dq] = v;
    *(float4*)(xconv + base) = v;
  }
  __syncthreads();

  // step 2: dbc = xc @ W_dbc (256 -> 48); thread tile 2 rows x 3 cols
  {
    const int ty = tid >> 4;          // 0..31 -> rows ty*2, ty*2+1
    const int tx = tid & 15;          // 0..15 -> cols tx*3..tx*3+2
    const int r0 = ty * 2, j0 = tx * 3;
    float acc[2][3] = {};
    #pragma unroll 4
    for (int k0 = 0; k0 < D_; k0 += 4) {
      const float4 x0 = *(const float4*)&xc[r0 + 0][k0];
      const float4 x1 = *(const float4*)&xc[r0 + 1][k0];
      const float4 w0 = *(const float4*)&wt[j0 + 0][k0];
      const float4 w1 = *(const float4*)&wt[j0 + 1][k0];
      const float4 w2 = *(const float4*)&wt[j0 + 2][k0];
      acc[0][0] += x0.x*w0.x + x0.y*w0.y + x0.z*w0.z + x0.w*w0.w;
      acc[0][1] += x0.x*w1.x + x0.y*w1.y + x0.z*w1.z + x0.w*w1.w;
      acc[0][2] += x0.x*w2.x + x0.y*w2.y + x0.z*w2.z + x0.w*w2.w;
      acc[1][0] += x1.x*w0.x + x1.y*w0.y + x1.z*w0.z + x1.w*w0.w;
      acc[1][1] += x1.x*w1.x + x1.y*w1.y + x1.z*w1.z + x1.w*w1.w;
      acc[1][2] += x1.x*w2.x + x1.y*w2.y + x1.z*w2.z + x1.w*w2.w;
    }
    #pragma unroll
    for (int i = 0; i < 2; ++i) {
      #pragma unroll
      for (int jj = 0; jj < 3; ++jj) {
        const float s = acc[i][jj];
        const int r = r0 + i, j = j0 + jj;
        const int l = l0 + r;
        if (j < DTR)            dlow[r][j] = s;
        else if (j < DTR + N_)  Bm[(b * L_ + l) * N_ + (j - DTR)] = s;
        else                    Cm[(b * L_ + l) * N_ + (j - DTR - N_)] = s;
      }
    }
  }
  __syncthreads();

  // step 3: delta = softplus(dlow @ W_dt + b_dt)  (16 -> 256), float4 over d
  for (int q = tid; q < 64 * 64; q += 512) {
    const int r = q >> 6, dq = (q & 63) * 4;
    float4 s = *(const float4*)(bdt + dq);
    #pragma unroll
    for (int k = 0; k < DTR; ++k) {
      const float f = dlow[r][k];
      const float4 wv = *(const float4*)(Wdt + k * D_ + dq);
      s.x = fmaf(f, wv.x, s.x); s.y = fmaf(f, wv.y, s.y);
      s.z = fmaf(f, wv.z, s.z); s.w = fmaf(f, wv.w, s.w);
    }
    float4 o;
    o.x = fmaxf(s.x, 0.f) + log1pf(expf(-fabsf(s.x)));
    o.y = fmaxf(s.y, 0.f) + log1pf(expf(-fabsf(s.y)));
    o.z = fmaxf(s.z, 0.f) + log1pf(expf(-fabsf(s.z)));
    o.w = fmaxf(s.w, 0.f) + log1pf(expf(-fabsf(s.w)));
    *(float4*)(delta + (b * L_ + (l0 + r)) * D_ + dq) = o;
  }
}

// --------- chunked selective scan: thread owns (b,chunk,d), n in regs ---------
__global__ __launch_bounds__(256) void scan_pass1_k(
    const float* __restrict__ delta, const float* __restrict__ xconv,
    const float* __restrict__ Bm, const float* __restrict__ A_log,
    float* __restrict__ Pp, float* __restrict__ Sp)
{
  const int gid = blockIdx.x * 256 + threadIdx.x;   // B*NC*D threads
  const int d = gid & 255;
  const int c = (gid >> 8) & (NC - 1);
  const int b = gid >> 15;
  float A[N_], P[N_], S[N_];
  #pragma unroll
  for (int n = 0; n < N_; ++n) {
    A[n] = -__expf(A_log[d * N_ + n]);
    P[n] = 1.f; S[n] = 0.f;
  }
  int base = (b * L_ + c * LC) * D_ + d;
  int bn   = (b * L_ + c * LC) * N_;
  #pragma unroll 2
  for (int t = 0; t < LC; ++t) {
    const float dv = delta[base];
    const float xv = xconv[base];
    const float dvx = dv * xv;
    float bv[N_];
    #pragma unroll
    for (int q = 0; q < 4; ++q) *(float4*)&bv[q * 4] = *(const float4*)(Bm + bn + q * 4);
    #pragma unroll
    for (int n = 0; n < N_; ++n) {
      const float a = __expf(dv * A[n]);
      S[n] = fmaf(a, S[n], dvx * bv[n]);
      P[n] *= a;
    }
    base += D_; bn += N_;
  }
  const int o = ((b * D_ + d) * NC + c) * N_;
  #pragma unroll
  for (int q = 0; q < 4; ++q) {
    *(float4*)(Pp + o + q * 4) = *(const float4*)&P[q * 4];
    *(float4*)(Sp + o + q * 4) = *(const float4*)&S[q * 4];
  }
}

// pass2: cross-chunk scan; Hin may alias Pp (read-before-write order)
__global__ __launch_bounds__(256) void scan_pass2_k(
    const float* Pp, const float* Sp, float* Hin)
{
  const int gid = blockIdx.x * 256 + threadIdx.x;   // B*D*N threads
  const int n = gid & 15;
  const int bd = gid >> 4;
  const int base = bd * NC * N_ + n;
  float h = 0.f;
  for (int c = 0; c < NC; ++c) {
    const int idx = base + c * N_;
    const float p = Pp[idx];
    const float s = Sp[idx];
    Hin[idx] = h;
    h = fmaf(p, h, s);
  }
}

// pass3: replay chunk from h_in, reduce y over n in-register
__global__ __launch_bounds__(256) void scan_pass3_k(
    const float* __restrict__ delta, const float* __restrict__ xconv,
    const float* __restrict__ Bm, const float* __restrict__ Cm,
    const float* __restrict__ A_log, const float* __restrict__ Dskip,
    const float* __restrict__ Hin, float* __restrict__ y)
{
  const int gid = blockIdx.x * 256 + threadIdx.x;   // B*NC*D threads
  const int d = gid & 255;
  const int c = (gid >> 8) & (NC - 1);
  const int b = gid >> 15;
  const float dsk = Dskip[d];
  float A[N_], h[N_];
  const int ho = ((b * D_ + d) * NC + c) * N_;
  #pragma unroll
  for (int n = 0; n < N_; ++n) A[n] = -__expf(A_log[d * N_ + n]);
  #pragma unroll
  for (int q = 0; q < 4; ++q) *(float4*)&h[q * 4] = *(const float4*)(Hin + ho + q * 4);
  int base = (b * L_ + c * LC) * D_ + d;
  int bn   = (b * L_ + c * LC) * N_;
  #pragma unroll 2
  for (int t = 0; t < LC; ++t) {
    const float dv = delta[base];
    const float xv = xconv[base];
    const float dvx = dv * xv;
    float bv[N_], cv[N_];
    #pragma unroll
    for (int q = 0; q < 4; ++q) {
      *(float4*)&bv[q * 4] = *(const float4*)(Bm + bn + q * 4);
      *(float4*)&cv[q * 4] = *(const float4*)(Cm + bn + q * 4);
    }
    float yv = dsk * xv;
    #pragma unroll
    for (int n = 0; n < N_; ++n) {
      const float a = __expf(dv * A[n]);
      h[n] = fmaf(a, h[n], dvx * bv[n]);
      yv = fmaf(h[n], cv[n], yv);
    }
    y[base] = yv;
    base += D_; bn += N_;
  }
}

extern "C" void kernel_launch(void* const* d_in, const int* in_sizes, int n_in,
                              void* d_out, int out_size, void* d_ws, size_t ws_size,
                              hipStream_t stream) {
  const float* x      = (const float*)d_in[0];
  const float* W_proj = (const float*)d_in[1];
  const float* b_proj = (const float*)d_in[2];
  const float* conv_w = (const float*)d_in[3];
  const float* conv_b = (const float*)d_in[4];
  const float* W_dbc  = (const float*)d_in[5];
  const float* W_dt   = (const float*)d_in[6];
  const float* b_dt   = (const float*)d_in[7];
  const float* A_log  = (const float*)d_in[8];
  const float* D_skip = (const float*)d_in[9];
  float* out = (float*)d_out;

  float* ws    = (float*)d_ws;
  const size_t SZ = (size_t)M_ * D_;        // 4M floats
  float* lin   = ws;
  float* xconv = ws + SZ;
  float* delta = ws + 2 * SZ;
  float* yb    = ws + 3 * SZ;
  float* Bm    = ws + 4 * SZ;
  float* Cm    = Bm + (size_t)M_ * N_;
  unsigned short* Wt = (unsigned short*)(Cm + (size_t)M_ * N_);  // 64K bf16
  // Pp/Sp live in d_out (dead until final GEMM); Hin aliases Pp (pass2 is
  // read-before-write at each index).
  const size_t PSZ = (size_t)B_ * D_ * NC * N_;   // 2M floats
  float* Pp  = out;
  float* Sp  = out + PSZ;
  float* Hin = Pp;

  // 0. Wt = bf16(W_proj^T)
  convert_w_k<<<dim3(256), dim3(256), 0, stream>>>(W_proj, Wt);
  // 1. lin = x @ W_proj + b_proj   (bf16 MFMA)
  gemm_mfma_k<0><<<dim3(512), dim3(256), 0, stream>>>(x, Wt, b_proj, nullptr, nullptr, lin);
  // 2. conv+silu -> xconv; dbc -> (dlow,B,C); delta = softplus(dlow@W_dt+b_dt)
  conv_dbc_delta_k<<<dim3(256), dim3(512), 0, stream>>>(
      lin, conv_w, conv_b, W_dbc, W_dt, b_dt, xconv, delta, Bm, Cm);
  // 3. chunked scan (NC=128 chunks of LC=32)
  scan_pass1_k<<<dim3(512), dim3(256), 0, stream>>>(delta, xconv, Bm, A_log, Pp, Sp);
  scan_pass2_k<<<dim3(64), dim3(256), 0, stream>>>(Pp, Sp, Hin);
  scan_pass3_k<<<dim3(512), dim3(256), 0, stream>>>(delta, xconv, Bm, Cm, A_log, D_skip, Hin, yb);
  // 4. out = (y*silu(lin)+x) @ W_proj + b_proj   (bf16 MFMA, gate fused)
  gemm_mfma_k<1><<<dim3(512), dim3(256), 0, stream>>>(yb, Wt, b_proj, lin, x, out);
}

// Round 5
// 124.021 us; speedup vs baseline: 2.4641x; 1.2961x over previous
//
#include <hip/hip_runtime.h>
#include <math.h>

#define B_ 4
#define L_ 4096
#define D_ 256
#define N_ 16
#define DTR 16
#define NC 128
#define LC 32
#define M_ (B_*L_)

typedef __attribute__((ext_vector_type(8))) short short8;
typedef __attribute__((ext_vector_type(4))) float floatx4;

__device__ __forceinline__ float silu_f(float v) { return v / (1.f + __expf(-v)); }

__device__ __forceinline__ unsigned short f2bf(float f) {
  union { float f; unsigned u; } v; v.f = f;
  unsigned r = (v.u + 0x7FFFu + ((v.u >> 16) & 1u)) >> 16;
  return (unsigned short)r;
}

// ---- one-time: Wt[n][k] = bf16(W[k][n]) ----
__global__ __launch_bounds__(256) void convert_w_k(
    const float* __restrict__ W, unsigned short* __restrict__ Wt)
{
  const int k = blockIdx.x;
  const int n = threadIdx.x;
  Wt[n * 256 + k] = f2bf(W[k * 256 + n]);
}

// ---------------- MFMA GEMM: C(M,256) = A(M,256) @ W + bias ----------------
template<int FUSE>
__global__ __launch_bounds__(256) void gemm_mfma_k(
    const float* __restrict__ Asrc, const unsigned short* __restrict__ Wt,
    const float* __restrict__ bias, const float* __restrict__ lin,
    const float* __restrict__ xin, float* __restrict__ Cout)
{
  __shared__ unsigned short Asl[32][40];    // 32 rows x 32 k (pad->40), bf16
  __shared__ unsigned short Wsl[256][40];   // 256 n  x 32 k (pad->40), bf16
  const int tid = threadIdx.x;
  const int lane = tid & 63, w = tid >> 6;
  const int row0 = blockIdx.x * 32;
  const int l15 = lane & 15, lg = lane >> 4;
  const int arow = (w & 1) * 16 + l15;      // A row this lane feeds
  const int ctile = (w >> 1) * 128;         // this wave's 128-col slab
  const int kk = lg * 8;                    // k-offset within 32-window
  floatx4 acc[8];
  #pragma unroll
  for (int f = 0; f < 8; ++f) acc[f] = (floatx4){0.f, 0.f, 0.f, 0.f};

  const int ar = tid >> 3, akc = (tid & 7) * 4;   // A staging coords
  const int wn = tid >> 2, wkc = (tid & 3) * 8;   // W staging coords

  for (int ks = 0; ks < 8; ++ks) {
    const int k0 = ks * 32;
    __syncthreads();
    {
      const int off = (row0 + ar) * 256 + k0 + akc;
      float4 av;
      if constexpr (FUSE) {
        float4 yv = *(const float4*)(Asrc + off);
        float4 lv = *(const float4*)(lin + off);
        float4 xv = *(const float4*)(xin + off);
        av.x = fmaf(yv.x, silu_f(lv.x), xv.x);
        av.y = fmaf(yv.y, silu_f(lv.y), xv.y);
        av.z = fmaf(yv.z, silu_f(lv.z), xv.z);
        av.w = fmaf(yv.w, silu_f(lv.w), xv.w);
      } else {
        av = *(const float4*)(Asrc + off);
      }
      unsigned short* p = &Asl[ar][akc];
      p[0] = f2bf(av.x); p[1] = f2bf(av.y); p[2] = f2bf(av.z); p[3] = f2bf(av.w);
    }
    #pragma unroll
    for (int i = 0; i < 4; ++i) {
      const int n = wn + i * 64;
      *(uint4*)&Wsl[n][wkc] = *(const uint4*)(Wt + n * 256 + k0 + wkc);
    }
    __syncthreads();
    const short8 af = *(const short8*)&Asl[arow][kk];
    #pragma unroll
    for (int f = 0; f < 8; ++f) {
      const short8 bf_ = *(const short8*)&Wsl[ctile + f * 16 + l15][kk];
      acc[f] = __builtin_amdgcn_mfma_f32_16x16x32_bf16(af, bf_, acc[f], 0, 0, 0);
    }
  }
  const int growb = row0 + (w & 1) * 16 + lg * 4;
  #pragma unroll
  for (int f = 0; f < 8; ++f) {
    const int col = ctile + f * 16 + l15;
    const float bb = bias[col];
    #pragma unroll
    for (int r = 0; r < 4; ++r)
      Cout[(growb + r) * 256 + col] = acc[f][r] + bb;
  }
}

// ------------- conv3(depthwise)+silu, dbc proj, delta proj -------------
#define XPAD 260

__global__ __launch_bounds__(512) void conv_dbc_delta_k(
    const float* __restrict__ lin, const float* __restrict__ conv_w,
    const float* __restrict__ conv_b, const float* __restrict__ Wdbc,
    const float* __restrict__ Wdt, const float* __restrict__ bdt,
    float* __restrict__ xconv, float* __restrict__ delta,
    float* __restrict__ Bm, float* __restrict__ Cm)
{
  __shared__ float xc[64][XPAD];     // 66.6 KB
  __shared__ float wt[48][XPAD];     // 49.9 KB  (W_dbc transposed: wt[j][k])
  __shared__ float dlow[64][17];     // 4.4 KB
  const int b  = blockIdx.x >> 6;    // 64 l-tiles per batch
  const int l0 = (blockIdx.x & 63) * 64;
  const int tid = threadIdx.x;

  for (int i = tid; i < 48 * D_; i += 512) {
    const int k = i / 48, j = i % 48;
    wt[j][k] = Wdbc[i];
  }

  for (int q = tid; q < 64 * 64; q += 512) {
    const int r = q >> 6, dq = (q & 63) * 4;
    const int l = l0 + r;
    const int base = (b * L_ + l) * D_ + dq;
    float4 c0 = (l > 0)      ? *(const float4*)(lin + base - D_) : make_float4(0,0,0,0);
    float4 c1 = *(const float4*)(lin + base);
    float4 c2 = (l < L_ - 1) ? *(const float4*)(lin + base + D_) : make_float4(0,0,0,0);
    float4 v;
    v.x = silu_f(c0.x*conv_w[(dq+0)*3+0] + c1.x*conv_w[(dq+0)*3+1] + c2.x*conv_w[(dq+0)*3+2] + conv_b[dq+0]);
    v.y = silu_f(c0.y*conv_w[(dq+1)*3+0] + c1.y*conv_w[(dq+1)*3+1] + c2.y*conv_w[(dq+1)*3+2] + conv_b[dq+1]);
    v.z = silu_f(c0.z*conv_w[(dq+2)*3+0] + c1.z*conv_w[(dq+2)*3+1] + c2.z*conv_w[(dq+2)*3+2] + conv_b[dq+2]);
    v.w = silu_f(c0.w*conv_w[(dq+3)*3+0] + c1.w*conv_w[(dq+3)*3+1] + c2.w*conv_w[(dq+3)*3+2] + conv_b[dq+3]);
    *(float4*)&xc[r][dq] = v;
    *(float4*)(xconv + base) = v;
  }
  __syncthreads();

  {
    const int ty = tid >> 4;
    const int tx = tid & 15;
    const int r0 = ty * 2, j0 = tx * 3;
    float acc[2][3] = {};
    #pragma unroll 4
    for (int k0 = 0; k0 < D_; k0 += 4) {
      const float4 x0 = *(const float4*)&xc[r0 + 0][k0];
      const float4 x1 = *(const float4*)&xc[r0 + 1][k0];
      const float4 w0 = *(const float4*)&wt[j0 + 0][k0];
      const float4 w1 = *(const float4*)&wt[j0 + 1][k0];
      const float4 w2 = *(const float4*)&wt[j0 + 2][k0];
      acc[0][0] += x0.x*w0.x + x0.y*w0.y + x0.z*w0.z + x0.w*w0.w;
      acc[0][1] += x0.x*w1.x + x0.y*w1.y + x0.z*w1.z + x0.w*w1.w;
      acc[0][2] += x0.x*w2.x + x0.y*w2.y + x0.z*w2.z + x0.w*w2.w;
      acc[1][0] += x1.x*w0.x + x1.y*w0.y + x1.z*w0.z + x1.w*w0.w;
      acc[1][1] += x1.x*w1.x + x1.y*w1.y + x1.z*w1.z + x1.w*w1.w;
      acc[1][2] += x1.x*w2.x + x1.y*w2.y + x1.z*w2.z + x1.w*w2.w;
    }
    #pragma unroll
    for (int i = 0; i < 2; ++i) {
      #pragma unroll
      for (int jj = 0; jj < 3; ++jj) {
        const float s = acc[i][jj];
        const int r = r0 + i, j = j0 + jj;
        const int l = l0 + r;
        if (j < DTR)            dlow[r][j] = s;
        else if (j < DTR + N_)  Bm[(b * L_ + l) * N_ + (j - DTR)] = s;
        else                    Cm[(b * L_ + l) * N_ + (j - DTR - N_)] = s;
      }
    }
  }
  __syncthreads();

  for (int q = tid; q < 64 * 64; q += 512) {
    const int r = q >> 6, dq = (q & 63) * 4;
    float4 s = *(const float4*)(bdt + dq);
    #pragma unroll
    for (int k = 0; k < DTR; ++k) {
      const float f = dlow[r][k];
      const float4 wv = *(const float4*)(Wdt + k * D_ + dq);
      s.x = fmaf(f, wv.x, s.x); s.y = fmaf(f, wv.y, s.y);
      s.z = fmaf(f, wv.z, s.z); s.w = fmaf(f, wv.w, s.w);
    }
    float4 o;
    o.x = fmaxf(s.x, 0.f) + log1pf(expf(-fabsf(s.x)));
    o.y = fmaxf(s.y, 0.f) + log1pf(expf(-fabsf(s.y)));
    o.z = fmaxf(s.z, 0.f) + log1pf(expf(-fabsf(s.z)));
    o.w = fmaxf(s.w, 0.f) + log1pf(expf(-fabsf(s.w)));
    *(float4*)(delta + (b * L_ + (l0 + r)) * D_ + dq) = o;
  }
}

// --------- chunked scan, N split across 2 threads (8 states each) ---------
// gid bits: [b:2][c:7][d:8][nh:1]
__global__ __launch_bounds__(256) void scan_pass1_k(
    const float* __restrict__ delta, const float* __restrict__ xconv,
    const float* __restrict__ Bm, const float* __restrict__ A_log,
    float* __restrict__ Pp, float* __restrict__ Sp)
{
  const int gid = blockIdx.x * 256 + threadIdx.x;   // B*NC*D*2 threads
  const int nh = gid & 1;
  const int d  = (gid >> 1) & 255;
  const int c  = (gid >> 9) & (NC - 1);
  const int b  = gid >> 16;
  const int n0 = nh * 8;
  float A[8], P[8], S[8];
  #pragma unroll
  for (int n = 0; n < 8; ++n) {
    A[n] = -__expf(A_log[d * N_ + n0 + n]);
    P[n] = 1.f; S[n] = 0.f;
  }
  int base = (b * L_ + c * LC) * D_ + d;
  int bn   = (b * L_ + c * LC) * N_ + n0;
  float dv = delta[base], xv = xconv[base];
  float4 bv0 = *(const float4*)(Bm + bn), bv1 = *(const float4*)(Bm + bn + 4);
  #pragma unroll 4
  for (int t = 0; t < LC; ++t) {
    const int nb = base + D_, nbn = bn + N_;
    const float dv_n = delta[nb];                 // prefetch t+1
    const float xv_n = xconv[nb];
    const float4 bv0n = *(const float4*)(Bm + nbn);
    const float4 bv1n = *(const float4*)(Bm + nbn + 4);
    const float dvx = dv * xv;
    float bv[8];
    *(float4*)&bv[0] = bv0; *(float4*)&bv[4] = bv1;
    #pragma unroll
    for (int n = 0; n < 8; ++n) {
      const float a = __expf(dv * A[n]);
      S[n] = fmaf(a, S[n], dvx * bv[n]);
      P[n] *= a;
    }
    dv = dv_n; xv = xv_n; bv0 = bv0n; bv1 = bv1n; base = nb; bn = nbn;
  }
  const int o = ((b * D_ + d) * NC + c) * N_ + n0;
  *(float4*)(Pp + o) = *(const float4*)&P[0];
  *(float4*)(Pp + o + 4) = *(const float4*)&P[4];
  *(float4*)(Sp + o) = *(const float4*)&S[0];
  *(float4*)(Sp + o + 4) = *(const float4*)&S[4];
}

// pass2: block per (b,d); Hillis-Steele scan over 128 chunks (affine compose)
__global__ __launch_bounds__(128) void scan_pass2_k(
    const float* Pp, const float* Sp, float* Hin)
{
  __shared__ float lP[N_][NC + 1];
  __shared__ float lS[N_][NC + 1];
  const int bd = blockIdx.x;                 // b*D + d
  const int c = threadIdx.x;                 // chunk
  const int base = bd * NC * N_ + c * N_;
  float P[N_], S[N_];
  #pragma unroll
  for (int q = 0; q < 4; ++q) {
    *(float4*)&P[q * 4] = *(const float4*)(Pp + base + q * 4);
    *(float4*)&S[q * 4] = *(const float4*)(Sp + base + q * 4);
  }
  #pragma unroll
  for (int n = 0; n < N_; ++n) { lP[n][c] = P[n]; lS[n][c] = S[n]; }
  for (int s = 1; s < NC; s <<= 1) {
    __syncthreads();
    float Pb[N_], Sb[N_];
    if (c >= s) {
      #pragma unroll
      for (int n = 0; n < N_; ++n) { Pb[n] = lP[n][c - s]; Sb[n] = lS[n][c - s]; }
    }
    __syncthreads();
    if (c >= s) {
      #pragma unroll
      for (int n = 0; n < N_; ++n) {
        S[n] = fmaf(P[n], Sb[n], S[n]);   // (P,S) ∘ (Pb,Sb)
        P[n] *= Pb[n];
        lP[n][c] = P[n]; lS[n][c] = S[n];
      }
    }
  }
  __syncthreads();
  float h[N_];
  if (c == 0) {
    #pragma unroll
    for (int n = 0; n < N_; ++n) h[n] = 0.f;
  } else {
    #pragma unroll
    for (int n = 0; n < N_; ++n) h[n] = lS[n][c - 1];
  }
  #pragma unroll
  for (int q = 0; q < 4; ++q)
    *(float4*)(Hin + base + q * 4) = *(const float4*)&h[q * 4];
}

// pass3: replay chunk from h_in; y reduced 8-in-reg + 1 shuffle
__global__ __launch_bounds__(256) void scan_pass3_k(
    const float* __restrict__ delta, const float* __restrict__ xconv,
    const float* __restrict__ Bm, const float* __restrict__ Cm,
    const float* __restrict__ A_log, const float* __restrict__ Dskip,
    const float* __restrict__ Hin, float* __restrict__ y)
{
  const int gid = blockIdx.x * 256 + threadIdx.x;   // B*NC*D*2 threads
  const int nh = gid & 1;
  const int d  = (gid >> 1) & 255;
  const int c  = (gid >> 9) & (NC - 1);
  const int b  = gid >> 16;
  const int n0 = nh * 8;
  const float dsk = Dskip[d];
  float A[8], h[8];
  const int ho = ((b * D_ + d) * NC + c) * N_ + n0;
  #pragma unroll
  for (int n = 0; n < 8; ++n) A[n] = -__expf(A_log[d * N_ + n0 + n]);
  *(float4*)&h[0] = *(const float4*)(Hin + ho);
  *(float4*)&h[4] = *(const float4*)(Hin + ho + 4);
  int base = (b * L_ + c * LC) * D_ + d;
  int bn   = (b * L_ + c * LC) * N_ + n0;
  float dv = delta[base], xv = xconv[base];
  float4 bv0 = *(const float4*)(Bm + bn), bv1 = *(const float4*)(Bm + bn + 4);
  float4 cv0 = *(const float4*)(Cm + bn), cv1 = *(const float4*)(Cm + bn + 4);
  #pragma unroll 4
  for (int t = 0; t < LC; ++t) {
    const int nb = base + D_, nbn = bn + N_;
    const float dv_n = delta[nb];                 // prefetch t+1
    const float xv_n = xconv[nb];
    const float4 bv0n = *(const float4*)(Bm + nbn);
    const float4 bv1n = *(const float4*)(Bm + nbn + 4);
    const float4 cv0n = *(const float4*)(Cm + nbn);
    const float4 cv1n = *(const float4*)(Cm + nbn + 4);
    const float dvx = dv * xv;
    float bv[8], cv[8];
    *(float4*)&bv[0] = bv0; *(float4*)&bv[4] = bv1;
    *(float4*)&cv[0] = cv0; *(float4*)&cv[4] = cv1;
    float p = 0.f;
    #pragma unroll
    for (int n = 0; n < 8; ++n) {
      const float a = __expf(dv * A[n]);
      h[n] = fmaf(a, h[n], dvx * bv[n]);
      p = fmaf(h[n], cv[n], p);
    }
    p += __shfl_xor(p, 1);
    if (nh == 0) y[base] = fmaf(dsk, xv, p);
    dv = dv_n; xv = xv_n; bv0 = bv0n; bv1 = bv1n; cv0 = cv0n; cv1 = cv1n;
    base = nb; bn = nbn;
  }
}

extern "C" void kernel_launch(void* const* d_in, const int* in_sizes, int n_in,
                              void* d_out, int out_size, void* d_ws, size_t ws_size,
                              hipStream_t stream) {
  const float* x      = (const float*)d_in[0];
  const float* W_proj = (const float*)d_in[1];
  const float* b_proj = (const float*)d_in[2];
  const float* conv_w = (const float*)d_in[3];
  const float* conv_b = (const float*)d_in[4];
  const float* W_dbc  = (const float*)d_in[5];
  const float* W_dt   = (const float*)d_in[6];
  const float* b_dt   = (const float*)d_in[7];
  const float* A_log  = (const float*)d_in[8];
  const float* D_skip = (const float*)d_in[9];
  float* out = (float*)d_out;

  float* ws    = (float*)d_ws;
  const size_t SZ = (size_t)M_ * D_;        // 4M floats
  float* lin   = ws;
  float* xconv = ws + SZ;
  float* delta = ws + 2 * SZ;
  float* yb    = ws + 3 * SZ;
  float* Bm    = ws + 4 * SZ;
  float* Cm    = Bm + (size_t)M_ * N_;
  unsigned short* Wt = (unsigned short*)(Cm + (size_t)M_ * N_);  // 64K bf16
  // Pp/Sp live in d_out (dead until final GEMM); Hin aliases Pp (pass2 reads
  // all of its block's Pp before writing Hin).
  const size_t PSZ = (size_t)B_ * D_ * NC * N_;   // 2M floats
  float* Pp  = out;
  float* Sp  = out + PSZ;
  float* Hin = Pp;

  convert_w_k<<<dim3(256), dim3(256), 0, stream>>>(W_proj, Wt);
  gemm_mfma_k<0><<<dim3(512), dim3(256), 0, stream>>>(x, Wt, b_proj, nullptr, nullptr, lin);
  conv_dbc_delta_k<<<dim3(256), dim3(512), 0, stream>>>(
      lin, conv_w, conv_b, W_dbc, W_dt, b_dt, xconv, delta, Bm, Cm);
  scan_pass1_k<<<dim3(1024), dim3(256), 0, stream>>>(delta, xconv, Bm, A_log, Pp, Sp);
  scan_pass2_k<<<dim3(1024), dim3(128), 0, stream>>>(Pp, Sp, Hin);
  scan_pass3_k<<<dim3(1024), dim3(256), 0, stream>>>(delta, xconv, Bm, Cm, A_log, D_skip, Hin, yb);
  gemm_mfma_k<1><<<dim3(512), dim3(256), 0, stream>>>(yb, Wt, b_proj, lin, x, out);
}

// Round 6
// 109.656 us; speedup vs baseline: 2.7869x; 1.1310x over previous
//
#include <hip/hip_runtime.h>
#include <math.h>

#define B_ 4
#define L_ 4096
#define D_ 256
#define N_ 16
#define DTR 16
#define NC 128
#define LC 32
#define M_ (B_*L_)

typedef __attribute__((ext_vector_type(8))) short short8;
typedef __attribute__((ext_vector_type(4))) float floatx4;

__device__ __forceinline__ float silu_f(float v) { return v / (1.f + __expf(-v)); }

__device__ __forceinline__ unsigned short f2bf(float f) {
  union { float f; unsigned u; } v; v.f = f;
  unsigned r = (v.u + 0x7FFFu + ((v.u >> 16) & 1u)) >> 16;
  return (unsigned short)r;
}

// fast softplus: max(x,0) + log(1+exp(-|x|)) via HW exp/log
__device__ __forceinline__ float softplus_f(float x) {
  return fmaxf(x, 0.f) + __logf(1.f + __expf(-fabsf(x)));
}

// ---- one-time: Wt[n][k] = bf16(W[k][n]) ----
__global__ __launch_bounds__(256) void convert_w_k(
    const float* __restrict__ W, unsigned short* __restrict__ Wt)
{
  const int k = blockIdx.x;
  const int n = threadIdx.x;
  Wt[n * 256 + k] = f2bf(W[k * 256 + n]);
}

// ---------------- MFMA GEMM: C(M,256) = A(M,256) @ W + bias ----------------
template<int FUSE>
__global__ __launch_bounds__(256) void gemm_mfma_k(
    const float* __restrict__ Asrc, const unsigned short* __restrict__ Wt,
    const float* __restrict__ bias, const float* __restrict__ lin,
    const float* __restrict__ xin, float* __restrict__ Cout)
{
  __shared__ unsigned short Asl[32][40];    // 32 rows x 32 k (pad->40), bf16
  __shared__ unsigned short Wsl[256][40];   // 256 n  x 32 k (pad->40), bf16
  const int tid = threadIdx.x;
  const int lane = tid & 63, w = tid >> 6;
  const int row0 = blockIdx.x * 32;
  const int l15 = lane & 15, lg = lane >> 4;
  const int arow = (w & 1) * 16 + l15;      // A row this lane feeds
  const int ctile = (w >> 1) * 128;         // this wave's 128-col slab
  const int kk = lg * 8;                    // k-offset within 32-window
  floatx4 acc[8];
  #pragma unroll
  for (int f = 0; f < 8; ++f) acc[f] = (floatx4){0.f, 0.f, 0.f, 0.f};

  const int ar = tid >> 3, akc = (tid & 7) * 4;   // A staging coords
  const int wn = tid >> 2, wkc = (tid & 3) * 8;   // W staging coords

  for (int ks = 0; ks < 8; ++ks) {
    const int k0 = ks * 32;
    __syncthreads();
    {
      const int off = (row0 + ar) * 256 + k0 + akc;
      float4 av;
      if constexpr (FUSE) {
        float4 yv = *(const float4*)(Asrc + off);
        float4 lv = *(const float4*)(lin + off);
        float4 xv = *(const float4*)(xin + off);
        av.x = fmaf(yv.x, silu_f(lv.x), xv.x);
        av.y = fmaf(yv.y, silu_f(lv.y), xv.y);
        av.z = fmaf(yv.z, silu_f(lv.z), xv.z);
        av.w = fmaf(yv.w, silu_f(lv.w), xv.w);
      } else {
        av = *(const float4*)(Asrc + off);
      }
      unsigned short* p = &Asl[ar][akc];
      p[0] = f2bf(av.x); p[1] = f2bf(av.y); p[2] = f2bf(av.z); p[3] = f2bf(av.w);
    }
    #pragma unroll
    for (int i = 0; i < 4; ++i) {
      const int n = wn + i * 64;
      *(uint4*)&Wsl[n][wkc] = *(const uint4*)(Wt + n * 256 + k0 + wkc);
    }
    __syncthreads();
    const short8 af = *(const short8*)&Asl[arow][kk];
    #pragma unroll
    for (int f = 0; f < 8; ++f) {
      const short8 bf_ = *(const short8*)&Wsl[ctile + f * 16 + l15][kk];
      acc[f] = __builtin_amdgcn_mfma_f32_16x16x32_bf16(af, bf_, acc[f], 0, 0, 0);
    }
  }
  const int growb = row0 + (w & 1) * 16 + lg * 4;
  #pragma unroll
  for (int f = 0; f < 8; ++f) {
    const int col = ctile + f * 16 + l15;
    const float bb = bias[col];
    #pragma unroll
    for (int r = 0; r < 4; ++r)
      Cout[(growb + r) * 256 + col] = acc[f][r] + bb;
  }
}

// ------------- conv3(depthwise)+silu -> xconv(f32)+LDS(bf16);
//               dbc = xc @ W_dbc via MFMA -> dlow/Bm/Cm;
//               delta = softplus(dlow @ W_dt + b_dt) -------------
__global__ __launch_bounds__(256) void conv_dbc_delta_k(
    const float* __restrict__ lin, const float* __restrict__ conv_w,
    const float* __restrict__ conv_b, const float* __restrict__ Wdbc,
    const float* __restrict__ Wdt, const float* __restrict__ bdt,
    float* __restrict__ xconv, float* __restrict__ delta,
    float* __restrict__ Bm, float* __restrict__ Cm)
{
  __shared__ unsigned short xcb[64][264];   // 33.8 KB  (bf16 conv output)
  __shared__ unsigned short wtb[48][264];   // 25.3 KB  (W_dbc^T bf16)
  __shared__ float dlow[64][17];            //  4.4 KB
  const int b  = blockIdx.x >> 6;           // 64 l-tiles per batch
  const int l0 = (blockIdx.x & 63) * 64;
  const int tid = threadIdx.x;
  const int lane = tid & 63, w = tid >> 6;
  const int l15 = lane & 15, lg = lane >> 4;

  // stage W_dbc transposed -> bf16 (thread tid owns k-row tid)
  {
    const float* src = Wdbc + tid * 48;
    #pragma unroll
    for (int j0 = 0; j0 < 12; ++j0) {
      const float4 v = *(const float4*)(src + j0 * 4);
      wtb[j0 * 4 + 0][tid] = f2bf(v.x);
      wtb[j0 * 4 + 1][tid] = f2bf(v.y);
      wtb[j0 * 4 + 2][tid] = f2bf(v.z);
      wtb[j0 * 4 + 3][tid] = f2bf(v.w);
    }
  }

  // conv + bias + silu, float4 over d; write f32 to global, bf16 to LDS
  for (int q = tid; q < 64 * 64; q += 256) {
    const int r = q >> 6, dq = (q & 63) * 4;
    const int l = l0 + r;
    const int base = (b * L_ + l) * D_ + dq;
    float4 c0 = (l > 0)      ? *(const float4*)(lin + base - D_) : make_float4(0,0,0,0);
    float4 c1 = *(const float4*)(lin + base);
    float4 c2 = (l < L_ - 1) ? *(const float4*)(lin + base + D_) : make_float4(0,0,0,0);
    float4 v;
    v.x = silu_f(c0.x*conv_w[(dq+0)*3+0] + c1.x*conv_w[(dq+0)*3+1] + c2.x*conv_w[(dq+0)*3+2] + conv_b[dq+0]);
    v.y = silu_f(c0.y*conv_w[(dq+1)*3+0] + c1.y*conv_w[(dq+1)*3+1] + c2.y*conv_w[(dq+1)*3+2] + conv_b[dq+1]);
    v.z = silu_f(c0.z*conv_w[(dq+2)*3+0] + c1.z*conv_w[(dq+2)*3+1] + c2.z*conv_w[(dq+2)*3+2] + conv_b[dq+2]);
    v.w = silu_f(c0.w*conv_w[(dq+3)*3+0] + c1.w*conv_w[(dq+3)*3+1] + c2.w*conv_w[(dq+3)*3+2] + conv_b[dq+3]);
    *(float4*)(xconv + base) = v;
    ushort4 bv;
    bv.x = f2bf(v.x); bv.y = f2bf(v.y); bv.z = f2bf(v.z); bv.w = f2bf(v.w);
    *(ushort4*)&xcb[r][dq] = bv;
  }
  __syncthreads();

  // dbc GEMM via MFMA: wave w owns rows w*16..w*16+15; 3 N-tiles (dlow|B|C)
  {
    const int arow = w * 16 + l15;
    const int kk0 = lg * 8;
    floatx4 acc[3];
    #pragma unroll
    for (int nt = 0; nt < 3; ++nt) acc[nt] = (floatx4){0.f, 0.f, 0.f, 0.f};
    #pragma unroll
    for (int ks = 0; ks < 8; ++ks) {
      const short8 af = *(const short8*)&xcb[arow][ks * 32 + kk0];
      #pragma unroll
      for (int nt = 0; nt < 3; ++nt) {
        const short8 bf_ = *(const short8*)&wtb[nt * 16 + l15][ks * 32 + kk0];
        acc[nt] = __builtin_amdgcn_mfma_f32_16x16x32_bf16(af, bf_, acc[nt], 0, 0, 0);
      }
    }
    // C layout: col=lane&15, row=(lane>>4)*4+reg
    const int row = w * 16 + lg * 4;
    const int gl = (b * L_ + l0 + row) * N_ + l15;
    #pragma unroll
    for (int r = 0; r < 4; ++r) {
      dlow[row + r][l15]   = acc[0][r];
      Bm[gl + r * N_]      = acc[1][r];
      Cm[gl + r * N_]      = acc[2][r];
    }
  }
  __syncthreads();

  // delta = softplus(dlow @ W_dt + b_dt), float4 over d; fast softplus
  for (int q = tid; q < 64 * 64; q += 256) {
    const int r = q >> 6, dq = (q & 63) * 4;
    float4 s = *(const float4*)(bdt + dq);
    #pragma unroll
    for (int k = 0; k < DTR; ++k) {
      const float f = dlow[r][k];
      const float4 wv = *(const float4*)(Wdt + k * D_ + dq);
      s.x = fmaf(f, wv.x, s.x); s.y = fmaf(f, wv.y, s.y);
      s.z = fmaf(f, wv.z, s.z); s.w = fmaf(f, wv.w, s.w);
    }
    float4 o;
    o.x = softplus_f(s.x); o.y = softplus_f(s.y);
    o.z = softplus_f(s.z); o.w = softplus_f(s.w);
    *(float4*)(delta + (b * L_ + (l0 + r)) * D_ + dq) = o;
  }
}

// --------- chunked scan, N split across 2 threads (8 states each) ---------
__global__ __launch_bounds__(256) void scan_pass1_k(
    const float* __restrict__ delta, const float* __restrict__ xconv,
    const float* __restrict__ Bm, const float* __restrict__ A_log,
    float* __restrict__ Pp, float* __restrict__ Sp)
{
  const int gid = blockIdx.x * 256 + threadIdx.x;   // B*NC*D*2 threads
  const int nh = gid & 1;
  const int d  = (gid >> 1) & 255;
  const int c  = (gid >> 9) & (NC - 1);
  const int b  = gid >> 16;
  const int n0 = nh * 8;
  float A[8], P[8], S[8];
  #pragma unroll
  for (int n = 0; n < 8; ++n) {
    A[n] = -__expf(A_log[d * N_ + n0 + n]);
    P[n] = 1.f; S[n] = 0.f;
  }
  int base = (b * L_ + c * LC) * D_ + d;
  int bn   = (b * L_ + c * LC) * N_ + n0;
  float dv = delta[base], xv = xconv[base];
  float4 bv0 = *(const float4*)(Bm + bn), bv1 = *(const float4*)(Bm + bn + 4);
  #pragma unroll 4
  for (int t = 0; t < LC; ++t) {
    const int nb = base + D_, nbn = bn + N_;
    const float dv_n = delta[nb];                 // prefetch t+1
    const float xv_n = xconv[nb];
    const float4 bv0n = *(const float4*)(Bm + nbn);
    const float4 bv1n = *(const float4*)(Bm + nbn + 4);
    const float dvx = dv * xv;
    float bv[8];
    *(float4*)&bv[0] = bv0; *(float4*)&bv[4] = bv1;
    #pragma unroll
    for (int n = 0; n < 8; ++n) {
      const float a = __expf(dv * A[n]);
      S[n] = fmaf(a, S[n], dvx * bv[n]);
      P[n] *= a;
    }
    dv = dv_n; xv = xv_n; bv0 = bv0n; bv1 = bv1n; base = nb; bn = nbn;
  }
  const int o = ((b * D_ + d) * NC + c) * N_ + n0;
  *(float4*)(Pp + o) = *(const float4*)&P[0];
  *(float4*)(Pp + o + 4) = *(const float4*)&P[4];
  *(float4*)(Sp + o) = *(const float4*)&S[0];
  *(float4*)(Sp + o + 4) = *(const float4*)&S[4];
}

// pass2: block per (b,d); Hillis-Steele scan over 128 chunks (affine compose)
__global__ __launch_bounds__(128) void scan_pass2_k(
    const float* Pp, const float* Sp, float* Hin)
{
  __shared__ float lP[N_][NC + 1];
  __shared__ float lS[N_][NC + 1];
  const int bd = blockIdx.x;                 // b*D + d
  const int c = threadIdx.x;                 // chunk
  const int base = bd * NC * N_ + c * N_;
  float P[N_], S[N_];
  #pragma unroll
  for (int q = 0; q < 4; ++q) {
    *(float4*)&P[q * 4] = *(const float4*)(Pp + base + q * 4);
    *(float4*)&S[q * 4] = *(const float4*)(Sp + base + q * 4);
  }
  #pragma unroll
  for (int n = 0; n < N_; ++n) { lP[n][c] = P[n]; lS[n][c] = S[n]; }
  for (int s = 1; s < NC; s <<= 1) {
    __syncthreads();
    float Pb[N_], Sb[N_];
    if (c >= s) {
      #pragma unroll
      for (int n = 0; n < N_; ++n) { Pb[n] = lP[n][c - s]; Sb[n] = lS[n][c - s]; }
    }
    __syncthreads();
    if (c >= s) {
      #pragma unroll
      for (int n = 0; n < N_; ++n) {
        S[n] = fmaf(P[n], Sb[n], S[n]);   // (P,S) ∘ (Pb,Sb)
        P[n] *= Pb[n];
        lP[n][c] = P[n]; lS[n][c] = S[n];
      }
    }
  }
  __syncthreads();
  float h[N_];
  if (c == 0) {
    #pragma unroll
    for (int n = 0; n < N_; ++n) h[n] = 0.f;
  } else {
    #pragma unroll
    for (int n = 0; n < N_; ++n) h[n] = lS[n][c - 1];
  }
  #pragma unroll
  for (int q = 0; q < 4; ++q)
    *(float4*)(Hin + base + q * 4) = *(const float4*)&h[q * 4];
}

// pass3: replay chunk from h_in; y reduced 8-in-reg + 1 shuffle
__global__ __launch_bounds__(256) void scan_pass3_k(
    const float* __restrict__ delta, const float* __restrict__ xconv,
    const float* __restrict__ Bm, const float* __restrict__ Cm,
    const float* __restrict__ A_log, const float* __restrict__ Dskip,
    const float* __restrict__ Hin, float* __restrict__ y)
{
  const int gid = blockIdx.x * 256 + threadIdx.x;   // B*NC*D*2 threads
  const int nh = gid & 1;
  const int d  = (gid >> 1) & 255;
  const int c  = (gid >> 9) & (NC - 1);
  const int b  = gid >> 16;
  const int n0 = nh * 8;
  const float dsk = Dskip[d];
  float A[8], h[8];
  const int ho = ((b * D_ + d) * NC + c) * N_ + n0;
  #pragma unroll
  for (int n = 0; n < 8; ++n) A[n] = -__expf(A_log[d * N_ + n0 + n]);
  *(float4*)&h[0] = *(const float4*)(Hin + ho);
  *(float4*)&h[4] = *(const float4*)(Hin + ho + 4);
  int base = (b * L_ + c * LC) * D_ + d;
  int bn   = (b * L_ + c * LC) * N_ + n0;
  float dv = delta[base], xv = xconv[base];
  float4 bv0 = *(const float4*)(Bm + bn), bv1 = *(const float4*)(Bm + bn + 4);
  float4 cv0 = *(const float4*)(Cm + bn), cv1 = *(const float4*)(Cm + bn + 4);
  #pragma unroll 4
  for (int t = 0; t < LC; ++t) {
    const int nb = base + D_, nbn = bn + N_;
    const float dv_n = delta[nb];                 // prefetch t+1
    const float xv_n = xconv[nb];
    const float4 bv0n = *(const float4*)(Bm + nbn);
    const float4 bv1n = *(const float4*)(Bm + nbn + 4);
    const float4 cv0n = *(const float4*)(Cm + nbn);
    const float4 cv1n = *(const float4*)(Cm + nbn + 4);
    const float dvx = dv * xv;
    float bv[8], cv[8];
    *(float4*)&bv[0] = bv0; *(float4*)&bv[4] = bv1;
    *(float4*)&cv[0] = cv0; *(float4*)&cv[4] = cv1;
    float p = 0.f;
    #pragma unroll
    for (int n = 0; n < 8; ++n) {
      const float a = __expf(dv * A[n]);
      h[n] = fmaf(a, h[n], dvx * bv[n]);
      p = fmaf(h[n], cv[n], p);
    }
    p += __shfl_xor(p, 1);
    if (nh == 0) y[base] = fmaf(dsk, xv, p);
    dv = dv_n; xv = xv_n; bv0 = bv0n; bv1 = bv1n; cv0 = cv0n; cv1 = cv1n;
    base = nb; bn = nbn;
  }
}

extern "C" void kernel_launch(void* const* d_in, const int* in_sizes, int n_in,
                              void* d_out, int out_size, void* d_ws, size_t ws_size,
                              hipStream_t stream) {
  const float* x      = (const float*)d_in[0];
  const float* W_proj = (const float*)d_in[1];
  const float* b_proj = (const float*)d_in[2];
  const float* conv_w = (const float*)d_in[3];
  const float* conv_b = (const float*)d_in[4];
  const float* W_dbc  = (const float*)d_in[5];
  const float* W_dt   = (const float*)d_in[6];
  const float* b_dt   = (const float*)d_in[7];
  const float* A_log  = (const float*)d_in[8];
  const float* D_skip = (const float*)d_in[9];
  float* out = (float*)d_out;

  float* ws    = (float*)d_ws;
  const size_t SZ = (size_t)M_ * D_;        // 4M floats
  float* lin   = ws;
  float* xconv = ws + SZ;
  float* delta = ws + 2 * SZ;
  float* yb    = ws + 3 * SZ;
  float* Bm    = ws + 4 * SZ;
  float* Cm    = Bm + (size_t)M_ * N_;
  unsigned short* Wt = (unsigned short*)(Cm + (size_t)M_ * N_);  // 64K bf16
  // Pp/Sp live in d_out (dead until final GEMM); Hin aliases Pp (pass2 reads
  // all of its block's Pp before writing Hin).
  const size_t PSZ = (size_t)B_ * D_ * NC * N_;   // 2M floats
  float* Pp  = out;
  float* Sp  = out + PSZ;
  float* Hin = Pp;

  convert_w_k<<<dim3(256), dim3(256), 0, stream>>>(W_proj, Wt);
  gemm_mfma_k<0><<<dim3(512), dim3(256), 0, stream>>>(x, Wt, b_proj, nullptr, nullptr, lin);
  conv_dbc_delta_k<<<dim3(256), dim3(256), 0, stream>>>(
      lin, conv_w, conv_b, W_dbc, W_dt, b_dt, xconv, delta, Bm, Cm);
  scan_pass1_k<<<dim3(1024), dim3(256), 0, stream>>>(delta, xconv, Bm, A_log, Pp, Sp);
  scan_pass2_k<<<dim3(1024), dim3(128), 0, stream>>>(Pp, Sp, Hin);
  scan_pass3_k<<<dim3(1024), dim3(256), 0, stream>>>(delta, xconv, Bm, Cm, A_log, D_skip, Hin, yb);
  gemm_mfma_k<1><<<dim3(512), dim3(256), 0, stream>>>(yb, Wt, b_proj, lin, x, out);
}